// Round 10
// baseline (1027.718 us; speedup 1.0000x reference)
//
#include <hip/hip_runtime.h>
#include <stdint.h>

typedef unsigned short u16;
typedef __attribute__((ext_vector_type(8))) short short8;
typedef __attribute__((ext_vector_type(4))) float f32x4;

#define MFMA16(A,B,C) __builtin_amdgcn_mfma_f32_16x16x32_bf16(A,B,C,0,0,0)

static __device__ __forceinline__ u16 f2bf(float f) {
  union { float f; unsigned u; } v; v.f = f;
  unsigned r = v.u + 0x7FFFu + ((v.u >> 16) & 1u);
  return (u16)(r >> 16);
}

static __device__ __forceinline__ void gload16(const void* g, void* l) {
  __builtin_amdgcn_global_load_lds(
      (const __attribute__((address_space(1))) void*)(uintptr_t)g,
      (__attribute__((address_space(3))) void*)(uint32_t)(uintptr_t)l,
      16, 0, 0);
}

// bijective XCD swizzle (m204)
static __device__ __forceinline__ int xcd_swz() {
  const int gx = gridDim.x, gy = gridDim.y, nwg = gx * gy;
  const int orig = blockIdx.y * gx + blockIdx.x;
  const int q = nwg >> 3, rm = nwg & 7, xcd = orig & 7, idx = orig >> 3;
  return (xcd < rm ? xcd * (q + 1) : rm * (q + 1) + (xcd - rm) * q) + idx;
}

// ======== 128x128 bf16 GEMM, A in registers, B-only LDS (r9 fixed) ==========
// r9 failed because TAIL vmcnt waits were removed and plain A-loads are
// compiler-reorderable vs gload_lds: the "transitive drain" assumption broke
// (prologue loadA could hoist above stageB, so vmcnt(8) retired A not B).
// Fix: explicit per-phase TAIL waits with ORDER-ROBUST counts. Phase-boundary
// "memory" asm fences pin inter-phase order; within a PRE (<=6 VMEM ops:
// 2 gload_lds + 4 A-loads) order is arbitrary, so counts assume the stage is
// the NEWEST op of its PRE: ops-after = two full PREs = 12 steady; edges
// 8 / 10 / 0. Prologue: vmcnt(4) BETWEEN stageBs and loadA (fence blocks the
// hoist) retires B(0,0). WAR seals unchanged from r8 (stage targets are
// regions whose readers passed a previous phase-end barrier via lgkmcnt(0)).
#define GPHASE(BUFO, KH, AF, PRE_STMT, TAIL_STMT) do { \
  short8 bf_[4]; \
  _Pragma("unroll") \
  for (int nf = 0; nf < 4; ++nf) { \
    const int r = wn0 + nf * 16 + colL; \
    bf_[nf] = *(const short8*)&lds[(BUFO) + ((KH) << 12) + r * 32 + ((kgr ^ ((r >> 1) & 3)) << 3)]; \
  } \
  PRE_STMT; \
  __builtin_amdgcn_s_barrier(); \
  asm volatile("s_waitcnt lgkmcnt(0)" ::: "memory"); \
  __builtin_amdgcn_sched_barrier(0); \
  __builtin_amdgcn_s_setprio(1); \
  _Pragma("unroll") \
  for (int mf = 0; mf < 4; ++mf) \
    _Pragma("unroll") \
    for (int nf = 0; nf < 4; ++nf) \
      acc[mf][nf] = MFMA16(AF[mf], bf_[nf], acc[mf][nf]); \
  __builtin_amdgcn_s_setprio(0); \
  __builtin_amdgcn_sched_barrier(0); \
  TAIL_STMT; \
  __builtin_amdgcn_s_barrier(); \
} while (0)

__global__ __launch_bounds__(256, 3) void gemm128p(
    const u16* __restrict__ A, const u16* __restrict__ Wt,
    float* __restrict__ Cf, u16* __restrict__ Cb,
    const float* __restrict__ bias,
    const float* __restrict__ res1, const float* __restrict__ res2,
    int M, int N, int K, int relu)
{
  __shared__ u16 lds[16384];  // 32 KiB: B only
  const int tid = threadIdx.x;
  const int wid = tid >> 6, lane = tid & 63;
  const int colL = lane & 15, kgr = lane >> 4;
  const int wm0 = (wid & 1) * 64, wn0 = (wid >> 1) * 64;
  const int w = xcd_swz();
  const int m0 = (w / gridDim.y) * 128, n0 = (w % gridDim.y) * 128;
  const int NT = K >> 6;
  f32x4 acc[4][4] = {};

  const u16* ap0 = A + (size_t)(m0 + wm0 +  0 + colL) * K + kgr * 8;
  const u16* ap1 = A + (size_t)(m0 + wm0 + 16 + colL) * K + kgr * 8;
  const u16* ap2 = A + (size_t)(m0 + wm0 + 32 + colL) * K + kgr * 8;
  const u16* ap3 = A + (size_t)(m0 + wm0 + 48 + colL) * K + kgr * 8;

  auto stageB = [&](int t_, int kh) {
    const int kb = t_ * 64 + kh * 32;
    const int base = ((t_ & 1) << 13) + (kh << 12);
#pragma unroll
    for (int i = 0; i < 2; ++i) {
      const int c = i * 256 + tid;
      const int row = c >> 2, slot = c & 3;
      gload16(Wt + (size_t)(n0 + row) * K + kb + ((slot ^ ((row >> 1) & 3)) << 3),
              &lds[base + ((i * 256 + wid * 64) << 3)]);
    }
  };

  short8 afA[4], afB[4];
  auto loadA = [&](short8* dst, int t_, int kh) {
    const int ko = t_ * 64 + kh * 32;
    dst[0] = *(const short8*)(ap0 + ko);
    dst[1] = *(const short8*)(ap1 + ko);
    dst[2] = *(const short8*)(ap2 + ko);
    dst[3] = *(const short8*)(ap3 + ko);
  };

  // prologue: stage B(0,0) B(0,1) B(1,0) (6 ops, ordered among themselves);
  // vmcnt(4) retires B(0,0) BEFORE loadA is issued (fence blocks hoisting);
  // afA(0,0) is guarded by the compiler's own wait before its MFMA use.
  stageB(0, 0); stageB(0, 1); stageB(1, 0);
  asm volatile("s_waitcnt vmcnt(4)" ::: "memory");
  loadA(afA, 0, 0);
  __builtin_amdgcn_s_barrier();

  for (int t = 0; t < NT; ++t) {
    const int bufo = (t & 1) << 13;
    // phase0: reads B(t,kh0); stages B(t+1,kh1) (other buf, sealed since
    // t-1 ph1); prefetches A(t,kh1). TAIL retires B(t,kh1) for next phase.
    GPHASE(bufo, 0, afA,
           { if (t + 1 < NT) stageB(t + 1, 1); loadA(afB, t, 1); },
           { if (t + 1 < NT) { asm volatile("s_waitcnt vmcnt(12)" ::: "memory"); }
             else            { asm volatile("s_waitcnt vmcnt(8)"  ::: "memory"); } });
    // phase1: reads B(t,kh1); stages B(t+2,kh0) (current buf kh0, sealed
    // after ph0's end barrier); prefetches A(t+1,kh0). TAIL retires B(t+1,kh0).
    GPHASE(bufo, 1, afB,
           { if (t + 2 < NT) stageB(t + 2, 0);
             if (t + 1 < NT) loadA(afA, t + 1, 0); },
           { if (t + 2 < NT)      { asm volatile("s_waitcnt vmcnt(12)" ::: "memory"); }
             else if (t + 1 < NT) { asm volatile("s_waitcnt vmcnt(10)" ::: "memory"); }
             else                 { asm volatile("s_waitcnt vmcnt(0)"  ::: "memory"); } });
  }

#pragma unroll
  for (int mf = 0; mf < 4; ++mf) {
#pragma unroll
    for (int nf = 0; nf < 4; ++nf) {
      const int n = n0 + wn0 + nf * 16 + colL;
      const float bv = bias ? bias[n] : 0.f;
#pragma unroll
      for (int rr = 0; rr < 4; ++rr) {
        const int m = m0 + wm0 + mf * 16 + kgr * 4 + rr;
        const size_t off = (size_t)m * N + n;
        float v = acc[mf][nf][rr] + bv;
        if (res1) v += res1[off];
        if (res2) v += res2[off];
        if (relu) v = fmaxf(v, 0.f);
        if (Cf) Cf[off] = v; else Cb[off] = f2bf(v);
      }
    }
  }
}

// ---------------- LayerNorm (fp32 in, bf16 out) -----------------------------
__global__ __launch_bounds__(256) void ln_rows(
    const float* __restrict__ x, const float* __restrict__ g,
    const float* __restrict__ bt, u16* __restrict__ out)
{
  const int row = blockIdx.x, tid = threadIdx.x;
  const float4 v = ((const float4*)(x + (size_t)row * 1024))[tid];
  float s  = v.x + v.y + v.z + v.w;
  float ss = v.x * v.x + v.y * v.y + v.z * v.z + v.w * v.w;
#pragma unroll
  for (int off = 32; off; off >>= 1) {
    s  += __shfl_xor(s, off);
    ss += __shfl_xor(ss, off);
  }
  __shared__ float red[8];
  const int wid = tid >> 6, lane = tid & 63;
  if (lane == 0) { red[wid] = s; red[4 + wid] = ss; }
  __syncthreads();
  s  = red[0] + red[1] + red[2] + red[3];
  ss = red[4] + red[5] + red[6] + red[7];
  const float mean = s * 0.0009765625f;
  const float var  = ss * 0.0009765625f - mean * mean;
  const float rstd = rsqrtf(var + 1e-5f);
  const float4 gg = ((const float4*)g)[tid];
  const float4 bb = ((const float4*)bt)[tid];
  uint2 ov;
  ov.x = (unsigned)f2bf((v.x - mean) * rstd * gg.x + bb.x) |
         ((unsigned)f2bf((v.y - mean) * rstd * gg.y + bb.y) << 16);
  ov.y = (unsigned)f2bf((v.z - mean) * rstd * gg.z + bb.z) |
         ((unsigned)f2bf((v.w - mean) * rstd * gg.w + bb.w) << 16);
  *(uint2*)(out + (size_t)row * 1024 + tid * 4) = ov;
}

// ---------------- weight packing --------------------------------------------
__global__ __launch_bounds__(256) void transpose_w(
    const float* __restrict__ in, u16* __restrict__ out, int R, int C)
{
  __shared__ float t[32][33];
  const int c0 = blockIdx.x * 32, r0 = blockIdx.y * 32;
  const int tx = threadIdx.x & 31, ty = threadIdx.x >> 5;
#pragma unroll
  for (int i = 0; i < 32; i += 8)
    t[ty + i][tx] = in[(size_t)(r0 + ty + i) * C + c0 + tx];
  __syncthreads();
#pragma unroll
  for (int i = 0; i < 32; i += 8)
    out[(size_t)(c0 + ty + i) * R + r0 + tx] = f2bf(t[tx][ty + i]);
}

__global__ __launch_bounds__(256) void pack_head_w(
    const float* __restrict__ w, u16* __restrict__ out)
{
  __shared__ float t[32][33];
  const int h = blockIdx.z;
  const int s0 = blockIdx.x * 32, c0 = blockIdx.y * 32;
  const int tx = threadIdx.x & 31, ty = threadIdx.x >> 5;
#pragma unroll
  for (int i = 0; i < 32; i += 8)
    t[ty + i][tx] = w[((size_t)h * 1024 + c0 + ty + i) * 64 + s0 + tx];
  __syncthreads();
#pragma unroll
  for (int i = 0; i < 32; i += 8)
    out[((size_t)h * 64 + s0 + ty + i) * 1024 + c0 + tx] = f2bf(t[tx][ty + i]);
}

__global__ __launch_bounds__(256) void cvt_bf16(
    const float* __restrict__ in, u16* __restrict__ out)
{
  const int i = blockIdx.x * blockDim.x + threadIdx.x;
  const float4 v = ((const float4*)in)[i];
  uint2 ov;
  ov.x = (unsigned)f2bf(v.x) | ((unsigned)f2bf(v.y) << 16);
  ov.y = (unsigned)f2bf(v.z) | ((unsigned)f2bf(v.w) << 16);
  *(uint2*)(out + (size_t)i * 4) = ov;
}

__global__ __launch_bounds__(256) void vtrans(
    const u16* __restrict__ src, u16* __restrict__ dst, int coloff, int ld)
{
  __shared__ u16 tile[64][65];
  const int t0 = blockIdx.x * 64, h = blockIdx.y, b = blockIdx.z;
  const int lr = threadIdx.x >> 4;
  const int lc = (threadIdx.x & 15) * 4;
#pragma unroll
  for (int i = 0; i < 64; i += 16) {
    const u16* sp = src + (size_t)(b * 1024 + t0 + lr + i) * ld + coloff + h * 64 + lc;
    const uint2 v = *(const uint2*)sp;
    tile[lr + i][lc + 0] = (u16)(v.x & 0xffff);
    tile[lr + i][lc + 1] = (u16)(v.x >> 16);
    tile[lr + i][lc + 2] = (u16)(v.y & 0xffff);
    tile[lr + i][lc + 3] = (u16)(v.y >> 16);
  }
  __syncthreads();
#pragma unroll
  for (int i = 0; i < 64; i += 16) {
    const int s = lr + i;
    uint2 ov;
    ov.x = (unsigned)tile[lc + 0][s] | ((unsigned)tile[lc + 1][s] << 16);
    ov.y = (unsigned)tile[lc + 2][s] | ((unsigned)tile[lc + 3][s] << 16);
    *(uint2*)(dst + (size_t)((b * 16 + h) * 64 + s) * 1024 + t0 + lc) = ov;
  }
}

// ---------------- inner causal flash attention ------------------------------
// grid (4, H, B): block p processes q-tiles (7-p) then (p) sequentially.
__global__ __launch_bounds__(512) void attn_inner(
    const u16* __restrict__ qkv, const u16* __restrict__ vt,
    u16* __restrict__ att)
{
  __shared__ u16 Kl[128 * 64];
  __shared__ u16 Vl[64 * 128];
  __shared__ u16 Pl[8 * 16 * 128];
  const int p = blockIdx.x, h = blockIdx.y, b = blockIdx.z;
  const int tid = threadIdx.x, wid = tid >> 6, lane = tid & 63;
  const int col = lane & 15, kgr = lane >> 4;
  const float scale = 0.03125f;
  u16* pw = &Pl[wid * 2048];

  auto run_q = [&](int tb) {
    short8 qf[2];
    {
      const int trow = tb * 128 + wid * 16 + col;
      const u16* qp = qkv + (size_t)(b * 1024 + trow) * 3072 + h * 64 + kgr * 8;
      qf[0] = *(const short8*)qp;
      qf[1] = *(const short8*)(qp + 32);
    }
    f32x4 o[4] = {};
    float mrun[4], lrun[4];
#pragma unroll
    for (int r = 0; r < 4; ++r) { mrun[r] = -1e30f; lrun[r] = 0.f; }

    for (int kt = 0; kt <= tb * 128; kt += 128) {
#pragma unroll
      for (int i = 0; i < 2; ++i) {
        const int e = i * 4096 + tid * 8;
        const int rk = e >> 6, uk = (e >> 3) & 7;
        gload16(qkv + (size_t)(b * 1024 + kt + rk) * 3072 + 1024 + h * 64 +
                    ((uk ^ (rk & 7)) << 3),
                &Kl[i * 4096 + wid * 512]);
        const int rv = e >> 7, uv = (e >> 3) & 15;
        gload16(vt + (size_t)((b * 16 + h) * 64 + rv) * 1024 + kt +
                    ((uv ^ (rv & 7)) << 3),
                &Vl[i * 4096 + wid * 512]);
      }
      __syncthreads();
      f32x4 s[8];
#pragma unroll
      for (int nt = 0; nt < 8; ++nt) {
        const int rk = nt * 16 + col;
        const short8 k0 = *(const short8*)&Kl[rk * 64 + ((kgr ^ (rk & 7)) << 3)];
        const short8 k1 = *(const short8*)&Kl[rk * 64 + (((kgr + 4) ^ (rk & 7)) << 3)];
        f32x4 a = {};
        a = MFMA16(qf[0], k0, a);
        a = MFMA16(qf[1], k1, a);
        s[nt] = a;
      }
      float mx[4];
#pragma unroll
      for (int r = 0; r < 4; ++r) mx[r] = -1e30f;
      const int tbase = tb * 128 + wid * 16 + kgr * 4;
      if (kt == tb * 128) {
#pragma unroll
        for (int nt = 0; nt < 8; ++nt) {
          const int kp = kt + nt * 16 + col;
#pragma unroll
          for (int r = 0; r < 4; ++r) {
            float v = s[nt][r] * scale;
            if (kp > tbase + r) v = -1e30f;
            s[nt][r] = v;
            mx[r] = fmaxf(mx[r], v);
          }
        }
      } else {
#pragma unroll
        for (int nt = 0; nt < 8; ++nt)
#pragma unroll
          for (int r = 0; r < 4; ++r) {
            const float v = s[nt][r] * scale;
            s[nt][r] = v;
            mx[r] = fmaxf(mx[r], v);
          }
      }
#pragma unroll
      for (int r = 0; r < 4; ++r)
#pragma unroll
        for (int off = 1; off < 16; off <<= 1)
          mx[r] = fmaxf(mx[r], __shfl_xor(mx[r], off));
      float f[4], rs[4];
#pragma unroll
      for (int r = 0; r < 4; ++r) {
        const float mn = fmaxf(mrun[r], mx[r]);
        f[r] = __expf(mrun[r] - mn);
        mrun[r] = mn;
        rs[r] = 0.f;
      }
#pragma unroll
      for (int nt = 0; nt < 8; ++nt)
#pragma unroll
        for (int r = 0; r < 4; ++r) {
          const float pv = __expf(s[nt][r] - mrun[r]);
          s[nt][r] = pv;
          rs[r] += pv;
        }
#pragma unroll
      for (int r = 0; r < 4; ++r) {
#pragma unroll
        for (int off = 1; off < 16; off <<= 1)
          rs[r] += __shfl_xor(rs[r], off);
        lrun[r] = lrun[r] * f[r] + rs[r];
      }
#pragma unroll
      for (int st = 0; st < 4; ++st)
#pragma unroll
        for (int r = 0; r < 4; ++r)
          o[st][r] *= f[r];
#pragma unroll
      for (int nt = 0; nt < 8; ++nt)
#pragma unroll
        for (int r = 0; r < 4; ++r) {
          const int rp = kgr * 4 + r;
          pw[rp * 128 + ((nt * 16 + col) ^ ((rp & 7) << 3))] = f2bf(s[nt][r]);
        }
#pragma unroll
      for (int ks = 0; ks < 4; ++ks) {
        const short8 pa = *(const short8*)&pw[col * 128 +
            ((ks * 32 + kgr * 8) ^ ((col & 7) << 3))];
#pragma unroll
        for (int st = 0; st < 4; ++st) {
          const int rv = st * 16 + col;
          const short8 vb = *(const short8*)&Vl[rv * 128 +
              (((ks * 4 + kgr) ^ (rv & 7)) << 3)];
          o[st] = MFMA16(pa, vb, o[st]);
        }
      }
      __syncthreads();
    }
#pragma unroll
    for (int r = 0; r < 4; ++r) {
      const float inv = 1.f / lrun[r];
      const int t = tb * 128 + wid * 16 + kgr * 4 + r;
#pragma unroll
      for (int st = 0; st < 4; ++st)
        att[(size_t)(b * 1024 + t) * 1024 + h * 64 + st * 16 + col] =
            f2bf(o[st][r] * inv);
    }
  };

  run_q(7 - p);
  run_q(p);
}

// ---------------- compressing cross attention -------------------------------
__global__ __launch_bounds__(512) void attn_cross(
    const u16* __restrict__ qv, const u16* __restrict__ kk,
    const u16* __restrict__ vt, u16* __restrict__ outc)
{
  __shared__ u16 KKl[256 * 64];
  __shared__ u16 Vl[64 * 128];
  __shared__ u16 PTl[256 * 128];
  const int h = blockIdx.x, b = blockIdx.y;
  const int tid = threadIdx.x, wid = tid >> 6, lane = tid & 63;
  const int col = lane & 15, kgr = lane >> 4;
  const float scale = 0.03125f;
#pragma unroll
  for (int i = 0; i < 4; ++i) {
    const int e = i * 4096 + tid * 8;
    const int rk = e >> 6, uk = (e >> 3) & 7;
    gload16(kk + (size_t)rk * 1024 + h * 64 + ((uk ^ (rk & 7)) << 3),
            &KKl[i * 4096 + wid * 512]);
  }
  f32x4 oacc[2][4] = {};
  for (int tt = 0; tt < 8; ++tt) {
    const int t0 = tt * 128;
#pragma unroll
    for (int i = 0; i < 2; ++i) {
      const int e = i * 4096 + tid * 8;
      const int rv = e >> 7, uv = (e >> 3) & 15;
      gload16(vt + (size_t)((b * 16 + h) * 64 + rv) * 1024 + t0 +
                  ((uv ^ (rv & 7)) << 3),
              &Vl[i * 4096 + wid * 512]);
    }
    short8 qf0, qf1;
    {
      const int trow = t0 + wid * 16 + col;
      const u16* qp = qv + (size_t)(b * 1024 + trow) * 2048 + h * 64 + kgr * 8;
      qf0 = *(const short8*)qp;
      qf1 = *(const short8*)(qp + 32);
    }
    __syncthreads();
    f32x4 s[16];
#pragma unroll
    for (int rt = 0; rt < 16; ++rt) {
      const int rk = rt * 16 + col;
      const short8 k0 = *(const short8*)&KKl[rk * 64 + ((kgr ^ (rk & 7)) << 3)];
      const short8 k1 = *(const short8*)&KKl[rk * 64 + (((kgr + 4) ^ (rk & 7)) << 3)];
      f32x4 a = {};
      a = MFMA16(qf0, k0, a);
      a = MFMA16(qf1, k1, a);
      s[rt] = a;
    }
    float mx[4];
#pragma unroll
    for (int r = 0; r < 4; ++r) mx[r] = -1e30f;
    const int tbase = t0 + wid * 16 + kgr * 4;
    if (t0 < 256) {
#pragma unroll
      for (int rt = 0; rt < 16; ++rt) {
        const int rp = rt * 16 + col;
#pragma unroll
        for (int r = 0; r < 4; ++r) {
          float v = s[rt][r] * scale;
          if (rp > tbase + r) v = -1e30f;
          s[rt][r] = v;
          mx[r] = fmaxf(mx[r], v);
        }
      }
    } else {
#pragma unroll
      for (int rt = 0; rt < 16; ++rt)
#pragma unroll
        for (int r = 0; r < 4; ++r) {
          const float v = s[rt][r] * scale;
          s[rt][r] = v;
          mx[r] = fmaxf(mx[r], v);
        }
    }
#pragma unroll
    for (int r = 0; r < 4; ++r)
#pragma unroll
      for (int off = 1; off < 16; off <<= 1)
        mx[r] = fmaxf(mx[r], __shfl_xor(mx[r], off));
    float sm[4];
#pragma unroll
    for (int r = 0; r < 4; ++r) sm[r] = 0.f;
#pragma unroll
    for (int rt = 0; rt < 16; ++rt)
#pragma unroll
      for (int r = 0; r < 4; ++r) {
        const float pv = __expf(s[rt][r] - mx[r]);
        s[rt][r] = pv;
        sm[r] += pv;
      }
#pragma unroll
    for (int r = 0; r < 4; ++r) {
#pragma unroll
      for (int off = 1; off < 16; off <<= 1)
        sm[r] += __shfl_xor(sm[r], off);
      sm[r] = 1.f / sm[r];
    }
#pragma unroll
    for (int rt = 0; rt < 16; ++rt)
#pragma unroll
      for (int r = 0; r < 4; ++r) {
        const int rpt = rt * 16 + col;
        PTl[rpt * 128 + ((wid * 16 + kgr * 4 + r) ^ ((rpt & 7) << 3))] =
            f2bf(s[rt][r] * sm[r]);
      }
    __syncthreads();
#pragma unroll
    for (int rr = 0; rr < 2; ++rr) {
      const int rb = (wid * 2 + rr) * 16;
#pragma unroll
      for (int ks = 0; ks < 4; ++ks) {
        const int rpt = rb + col;
        const short8 pa = *(const short8*)&PTl[rpt * 128 +
            ((ks * 32 + kgr * 8) ^ ((rpt & 7) << 3))];
#pragma unroll
        for (int st = 0; st < 4; ++st) {
          const int rv = st * 16 + col;
          const short8 vb = *(const short8*)&Vl[rv * 128 +
              (((ks * 4 + kgr) ^ (rv & 7)) << 3)];
          oacc[rr][st] = MFMA16(pa, vb, oacc[rr][st]);
        }
      }
    }
    __syncthreads();
  }
#pragma unroll
  for (int rr = 0; rr < 2; ++rr)
#pragma unroll
    for (int st = 0; st < 4; ++st)
#pragma unroll
      for (int r = 0; r < 4; ++r) {
        const int rpos = (wid * 2 + rr) * 16 + kgr * 4 + r;
        outc[(size_t)(b * 256 + rpos) * 1024 + h * 64 + st * 16 + col] =
            f2bf(oacc[rr][st][r]);
      }
}

// ---------------- host orchestration ----------------------------------------
extern "C" void kernel_launch(void* const* d_in, const int* in_sizes, int n_in,
                              void* d_out, int out_size, void* d_ws, size_t ws_size,
                              hipStream_t stream)
{
  const float* x     = (const float*)d_in[0];
  const float* pos   = (const float*)d_in[1];
  const float* bln1g = (const float*)d_in[2];
  const float* bln1b = (const float*)d_in[3];
  const float* bwq   = (const float*)d_in[4];
  const float* bwk   = (const float*)d_in[5];
  const float* bwv   = (const float*)d_in[6];
  const float* bwo   = (const float*)d_in[7];
  const float* bbo   = (const float*)d_in[8];
  const float* bln2g = (const float*)d_in[9];
  const float* bln2b = (const float*)d_in[10];
  const float* bw1   = (const float*)d_in[11];
  const float* bb1   = (const float*)d_in[12];
  const float* bw2   = (const float*)d_in[13];
  const float* bb2   = (const float*)d_in[14];
  const float* ln1g  = (const float*)d_in[15];
  const float* ln1b  = (const float*)d_in[16];
  const float* cwq   = (const float*)d_in[17];
  const float* cwk   = (const float*)d_in[18];
  const float* cwv   = (const float*)d_in[19];
  const float* cwo   = (const float*)d_in[20];
  const float* cbo   = (const float*)d_in[21];
  const float* cln2g = (const float*)d_in[22];
  const float* cln2b = (const float*)d_in[23];
  const float* fw1   = (const float*)d_in[24];
  const float* fb1   = (const float*)d_in[25];
  const float* fw2   = (const float*)d_in[26];
  const float* fb2   = (const float*)d_in[27];

  char* ws = (char*)d_ws;
  size_t off = 0;
  auto alloc = [&](size_t bytes) -> void* {
    void* p = ws + off; off += (bytes + 255) & ~(size_t)255; return p;
  };
  u16* wqkv_t = (u16*)alloc((size_t)3072 * 1024 * 2);
  u16* wo_t   = (u16*)alloc((size_t)1024 * 1024 * 2);
  u16* w1_t   = (u16*)alloc((size_t)4096 * 1024 * 2);
  u16* w2_t   = (u16*)alloc((size_t)1024 * 4096 * 2);
  u16* cwqv_t = (u16*)alloc((size_t)2048 * 1024 * 2);
  u16* cwk_t  = (u16*)alloc((size_t)1024 * 1024 * 2);
  u16* cwo_t  = (u16*)alloc((size_t)1024 * 1024 * 2);
  u16* fw1_t  = (u16*)alloc((size_t)4096 * 1024 * 2);
  u16* fw2_t  = (u16*)alloc((size_t)1024 * 4096 * 2);
  u16* pos_bf = (u16*)alloc((size_t)256 * 1024 * 2);
  u16* kkb    = (u16*)alloc((size_t)256 * 1024 * 2);
  u16* act_ln = (u16*)alloc((size_t)8192 * 1024 * 2);
  u16* qkv    = (u16*)alloc((size_t)8192 * 3072 * 2);
  u16* att    = (u16*)alloc((size_t)8192 * 1024 * 2);
  u16* ffb    = (u16*)alloc((size_t)8192 * 4096 * 2);
  float* yb   = (float*)alloc((size_t)8192 * 1024 * 4);
  if (ws_size < off) return;
  float* x2   = (float*)qkv;
  u16*   qv   = qkv;
  u16*   vt   = ffb;
  u16*   outc = att;
  float* zb   = yb;
  float* outp = (float*)d_out;

  const dim3 B256(256), B512(512);
  pack_head_w<<<dim3(2, 32, 16), B256, 0, stream>>>(bwq, wqkv_t);
  pack_head_w<<<dim3(2, 32, 16), B256, 0, stream>>>(bwk, wqkv_t + 1024 * 1024);
  pack_head_w<<<dim3(2, 32, 16), B256, 0, stream>>>(bwv, wqkv_t + 2048 * 1024);
  transpose_w<<<dim3(32, 32),  B256, 0, stream>>>(bwo, wo_t, 1024, 1024);
  transpose_w<<<dim3(128, 32), B256, 0, stream>>>(bw1, w1_t, 1024, 4096);
  transpose_w<<<dim3(32, 128), B256, 0, stream>>>(bw2, w2_t, 4096, 1024);
  pack_head_w<<<dim3(2, 32, 16), B256, 0, stream>>>(cwq, cwqv_t);
  pack_head_w<<<dim3(2, 32, 16), B256, 0, stream>>>(cwv, cwqv_t + 1024 * 1024);
  pack_head_w<<<dim3(2, 32, 16), B256, 0, stream>>>(cwk, cwk_t);
  transpose_w<<<dim3(32, 32),  B256, 0, stream>>>(cwo, cwo_t, 1024, 1024);
  transpose_w<<<dim3(128, 32), B256, 0, stream>>>(fw1, fw1_t, 1024, 4096);
  transpose_w<<<dim3(32, 128), B256, 0, stream>>>(fw2, fw2_t, 4096, 1024);
  cvt_bf16<<<dim3(256), B256, 0, stream>>>(pos, pos_bf);

  // ---- inner standard block ----
  ln_rows<<<dim3(8192), B256, 0, stream>>>(x, bln1g, bln1b, act_ln);
  gemm128p<<<dim3(64, 24), B256, 0, stream>>>(act_ln, wqkv_t, nullptr, qkv,
      nullptr, nullptr, nullptr, 8192, 3072, 1024, 0);
  vtrans<<<dim3(16, 16, 8), B256, 0, stream>>>(qkv, vt, 2048, 3072);
  attn_inner<<<dim3(4, 16, 8), B512, 0, stream>>>(qkv, vt, att);
  gemm128p<<<dim3(64, 8), B256, 0, stream>>>(att, wo_t, yb, nullptr,
      bbo, x, nullptr, 8192, 1024, 1024, 0);
  ln_rows<<<dim3(8192), B256, 0, stream>>>(yb, bln2g, bln2b, act_ln);
  gemm128p<<<dim3(64, 32), B256, 0, stream>>>(act_ln, w1_t, nullptr, ffb,
      bb1, nullptr, nullptr, 8192, 4096, 1024, 1);
  gemm128p<<<dim3(64, 8), B256, 0, stream>>>(ffb, w2_t, x2, nullptr,
      bb2, yb, x, 8192, 1024, 4096, 0);

  // ---- compressing cross-attention ----
  ln_rows<<<dim3(8192), B256, 0, stream>>>(x2, ln1g, ln1b, act_ln);
  gemm128p<<<dim3(64, 16), B256, 0, stream>>>(act_ln, cwqv_t, nullptr, qv,
      nullptr, nullptr, nullptr, 8192, 2048, 1024, 0);
  gemm128p<<<dim3(2, 8), B256, 0, stream>>>(pos_bf, cwk_t, nullptr, kkb,
      nullptr, nullptr, nullptr, 256, 1024, 1024, 0);
  vtrans<<<dim3(16, 16, 8), B256, 0, stream>>>(qv, vt, 1024, 2048);
  attn_cross<<<dim3(16, 8), B512, 0, stream>>>(qv, kkb, vt, outc);
  gemm128p<<<dim3(16, 8), B256, 0, stream>>>(outc, cwo_t, zb, nullptr,
      cbo, nullptr, nullptr, 2048, 1024, 1024, 0);

  // ---- final FFN ----
  ln_rows<<<dim3(2048), B256, 0, stream>>>(zb, cln2g, cln2b, act_ln);
  gemm128p<<<dim3(16, 32), B256, 0, stream>>>(act_ln, fw1_t, nullptr, ffb,
      fb1, nullptr, nullptr, 2048, 4096, 1024, 1);
  gemm128p<<<dim3(16, 8), B256, 0, stream>>>(ffb, fw2_t, outp, nullptr,
      fb2, zb, nullptr, 2048, 1024, 4096, 0);
}

// Round 11
// 800.629 us; speedup vs baseline: 1.2836x; 1.2836x over previous
//
#include <hip/hip_runtime.h>
#include <stdint.h>

typedef unsigned short u16;
typedef __attribute__((ext_vector_type(8))) short short8;
typedef __attribute__((ext_vector_type(4))) float f32x4;

#define MFMA16(A,B,C) __builtin_amdgcn_mfma_f32_16x16x32_bf16(A,B,C,0,0,0)

static __device__ __forceinline__ u16 f2bf(float f) {
  union { float f; unsigned u; } v; v.f = f;
  unsigned r = v.u + 0x7FFFu + ((v.u >> 16) & 1u);
  return (u16)(r >> 16);
}

static __device__ __forceinline__ void gload16(const void* g, void* l) {
  __builtin_amdgcn_global_load_lds(
      (const __attribute__((address_space(1))) void*)(uintptr_t)g,
      (__attribute__((address_space(3))) void*)(uint32_t)(uintptr_t)l,
      16, 0, 0);
}

// bijective XCD swizzle (m204)
static __device__ __forceinline__ int xcd_swz() {
  const int gx = gridDim.x, gy = gridDim.y, nwg = gx * gy;
  const int orig = blockIdx.y * gx + blockIdx.x;
  const int q = nwg >> 3, rm = nwg & 7, xcd = orig & 7, idx = orig >> 3;
  return (xcd < rm ? xcd * (q + 1) : rm * (q + 1) + (xcd - rm) * q) + idx;
}

// ======== 256x128 bf16 GEMM, BK=32, triple-buffered LDS (r8 skeleton) =======
// r10 post-mortem: A-in-VGPR was latency-bound (1-phase lookahead << load
// latency). Back to both-operands-in-LDS (r8, proven), but with a better
// traffic ratio: 256x128 tile, 4 waves 2m x 2n, 128x64/wave (acc 8x4).
// LDS = 3 bufs x [A 256rows | B 128rows] x 32cols x 2B = 72 KB -> 2 blk/CU.
// Per-FLOP LDS bytes 45.7 -> 34 B/KFLOP; 32 MFMAs per barrier-pair (was 16).
// Pipeline ledger (r8 shape): stage unit = 6 gload16/thread; prologue
// stage(0),stage(1) then vmcnt(6) (=stage(0) done); phase t reads buf[t%3],
// stages t+2 into buf[(t+2)%3] whose reader (t-1) was sealed at its end
// barrier (all waves drained own ds_reads at their lgkmcnt(0) before it).
// TAIL: steady in-flight 12 -> vmcnt(6) retires stage(t+1); edges vmcnt(0).
// XOR swizzle (row>>1)&3 on 16B slots, pre-swizzled source (0 conflicts
// r4-r10 PMC).
#define GPH(CUR, STAGE_STMT, TAIL_STMT) do { \
  short8 af_[8], bf_[4]; \
  _Pragma("unroll") \
  for (int mf = 0; mf < 8; ++mf) { \
    const int r = wm0 + mf * 16 + colL; \
    af_[mf] = *(const short8*)&lds[(CUR) + r * 32 + ((kgr ^ ((r >> 1) & 3)) << 3)]; \
  } \
  _Pragma("unroll") \
  for (int nf = 0; nf < 4; ++nf) { \
    const int r = wn0 + nf * 16 + colL; \
    bf_[nf] = *(const short8*)&lds[(CUR) + (256 + r) * 32 + ((kgr ^ ((r >> 1) & 3)) << 3)]; \
  } \
  STAGE_STMT; \
  __builtin_amdgcn_s_barrier(); \
  asm volatile("s_waitcnt lgkmcnt(0)" ::: "memory"); \
  __builtin_amdgcn_sched_barrier(0); \
  __builtin_amdgcn_s_setprio(1); \
  _Pragma("unroll") \
  for (int mf = 0; mf < 8; ++mf) \
    _Pragma("unroll") \
    for (int nf = 0; nf < 4; ++nf) \
      acc[mf][nf] = MFMA16(af_[mf], bf_[nf], acc[mf][nf]); \
  __builtin_amdgcn_s_setprio(0); \
  __builtin_amdgcn_sched_barrier(0); \
  TAIL_STMT; \
  __builtin_amdgcn_s_barrier(); \
} while (0)

__global__ __launch_bounds__(256, 2) void gemm256n(
    const u16* __restrict__ A, const u16* __restrict__ Wt,
    float* __restrict__ Cf, u16* __restrict__ Cb,
    const float* __restrict__ bias,
    const float* __restrict__ res1, const float* __restrict__ res2,
    int M, int N, int K, int relu)
{
  __shared__ u16 lds[36864];  // 72 KiB = 3 bufs x 12288 elems
  const int tid = threadIdx.x;
  const int wid = tid >> 6, lane = tid & 63;
  const int colL = lane & 15, kgr = lane >> 4;
  const int wm0 = (wid & 1) * 128, wn0 = (wid >> 1) * 64;
  const int w = xcd_swz();
  const int m0 = (w / gridDim.y) * 256, n0 = (w % gridDim.y) * 128;
  const int NT = K >> 5;
  f32x4 acc[8][4] = {};

  // stage one K-tile (t_): rows 0..255 = A[m0+..], rows 256..383 = B[n0+..].
  auto stage = [&](int t_, int bufo) {
    const int kb = t_ * 32;
#pragma unroll
    for (int i = 0; i < 4; ++i) {  // A rows
      const int c = i * 256 + tid;
      const int row = c >> 2, slot = c & 3;
      gload16(A + (size_t)(m0 + row) * K + kb + ((slot ^ ((row >> 1) & 3)) << 3),
              &lds[bufo + ((i * 256 + wid * 64) << 3)]);
    }
#pragma unroll
    for (int i = 4; i < 6; ++i) {  // B rows
      const int c = i * 256 + tid;
      const int row = c >> 2, slot = c & 3;   // row in 256..383
      gload16(Wt + (size_t)(n0 + row - 256) * K + kb + ((slot ^ ((row >> 1) & 3)) << 3),
              &lds[bufo + ((i * 256 + wid * 64) << 3)]);
    }
  };

  int c0 = 0, c1 = 12288, c2 = 24576;
  stage(0, c0); stage(1, c1);
  asm volatile("s_waitcnt vmcnt(6)" ::: "memory");  // stage(0) done
  __builtin_amdgcn_s_barrier();

  for (int t = 0; t < NT; ++t) {
    GPH(c0,
        { if (t + 2 < NT) stage(t + 2, c2); },
        { if (t + 2 < NT) { asm volatile("s_waitcnt vmcnt(6)" ::: "memory"); }
          else            { asm volatile("s_waitcnt vmcnt(0)" ::: "memory"); } });
    const int tmp = c0; c0 = c1; c1 = c2; c2 = tmp;
  }

#pragma unroll
  for (int mf = 0; mf < 8; ++mf) {
#pragma unroll
    for (int nf = 0; nf < 4; ++nf) {
      const int n = n0 + wn0 + nf * 16 + colL;
      const float bv = bias ? bias[n] : 0.f;
#pragma unroll
      for (int rr = 0; rr < 4; ++rr) {
        const int m = m0 + wm0 + mf * 16 + kgr * 4 + rr;
        const size_t off = (size_t)m * N + n;
        float v = acc[mf][nf][rr] + bv;
        if (res1) v += res1[off];
        if (res2) v += res2[off];
        if (relu) v = fmaxf(v, 0.f);
        if (Cf) Cf[off] = v; else Cb[off] = f2bf(v);
      }
    }
  }
}

// ---------------- LayerNorm (fp32 in, bf16 out) -----------------------------
__global__ __launch_bounds__(256) void ln_rows(
    const float* __restrict__ x, const float* __restrict__ g,
    const float* __restrict__ bt, u16* __restrict__ out)
{
  const int row = blockIdx.x, tid = threadIdx.x;
  const float4 v = ((const float4*)(x + (size_t)row * 1024))[tid];
  float s  = v.x + v.y + v.z + v.w;
  float ss = v.x * v.x + v.y * v.y + v.z * v.z + v.w * v.w;
#pragma unroll
  for (int off = 32; off; off >>= 1) {
    s  += __shfl_xor(s, off);
    ss += __shfl_xor(ss, off);
  }
  __shared__ float red[8];
  const int wid = tid >> 6, lane = tid & 63;
  if (lane == 0) { red[wid] = s; red[4 + wid] = ss; }
  __syncthreads();
  s  = red[0] + red[1] + red[2] + red[3];
  ss = red[4] + red[5] + red[6] + red[7];
  const float mean = s * 0.0009765625f;
  const float var  = ss * 0.0009765625f - mean * mean;
  const float rstd = rsqrtf(var + 1e-5f);
  const float4 gg = ((const float4*)g)[tid];
  const float4 bb = ((const float4*)bt)[tid];
  uint2 ov;
  ov.x = (unsigned)f2bf((v.x - mean) * rstd * gg.x + bb.x) |
         ((unsigned)f2bf((v.y - mean) * rstd * gg.y + bb.y) << 16);
  ov.y = (unsigned)f2bf((v.z - mean) * rstd * gg.z + bb.z) |
         ((unsigned)f2bf((v.w - mean) * rstd * gg.w + bb.w) << 16);
  *(uint2*)(out + (size_t)row * 1024 + tid * 4) = ov;
}

// ---------------- weight packing --------------------------------------------
__global__ __launch_bounds__(256) void transpose_w(
    const float* __restrict__ in, u16* __restrict__ out, int R, int C)
{
  __shared__ float t[32][33];
  const int c0 = blockIdx.x * 32, r0 = blockIdx.y * 32;
  const int tx = threadIdx.x & 31, ty = threadIdx.x >> 5;
#pragma unroll
  for (int i = 0; i < 32; i += 8)
    t[ty + i][tx] = in[(size_t)(r0 + ty + i) * C + c0 + tx];
  __syncthreads();
#pragma unroll
  for (int i = 0; i < 32; i += 8)
    out[(size_t)(c0 + ty + i) * R + r0 + tx] = f2bf(t[tx][ty + i]);
}

__global__ __launch_bounds__(256) void pack_head_w(
    const float* __restrict__ w, u16* __restrict__ out)
{
  __shared__ float t[32][33];
  const int h = blockIdx.z;
  const int s0 = blockIdx.x * 32, c0 = blockIdx.y * 32;
  const int tx = threadIdx.x & 31, ty = threadIdx.x >> 5;
#pragma unroll
  for (int i = 0; i < 32; i += 8)
    t[ty + i][tx] = w[((size_t)h * 1024 + c0 + ty + i) * 64 + s0 + tx];
  __syncthreads();
#pragma unroll
  for (int i = 0; i < 32; i += 8)
    out[((size_t)h * 64 + s0 + ty + i) * 1024 + c0 + tx] = f2bf(t[tx][ty + i]);
}

__global__ __launch_bounds__(256) void cvt_bf16(
    const float* __restrict__ in, u16* __restrict__ out)
{
  const int i = blockIdx.x * blockDim.x + threadIdx.x;
  const float4 v = ((const float4*)in)[i];
  uint2 ov;
  ov.x = (unsigned)f2bf(v.x) | ((unsigned)f2bf(v.y) << 16);
  ov.y = (unsigned)f2bf(v.z) | ((unsigned)f2bf(v.w) << 16);
  *(uint2*)(out + (size_t)i * 4) = ov;
}

__global__ __launch_bounds__(256) void vtrans(
    const u16* __restrict__ src, u16* __restrict__ dst, int coloff, int ld)
{
  __shared__ u16 tile[64][65];
  const int t0 = blockIdx.x * 64, h = blockIdx.y, b = blockIdx.z;
  const int lr = threadIdx.x >> 4;
  const int lc = (threadIdx.x & 15) * 4;
#pragma unroll
  for (int i = 0; i < 64; i += 16) {
    const u16* sp = src + (size_t)(b * 1024 + t0 + lr + i) * ld + coloff + h * 64 + lc;
    const uint2 v = *(const uint2*)sp;
    tile[lr + i][lc + 0] = (u16)(v.x & 0xffff);
    tile[lr + i][lc + 1] = (u16)(v.x >> 16);
    tile[lr + i][lc + 2] = (u16)(v.y & 0xffff);
    tile[lr + i][lc + 3] = (u16)(v.y >> 16);
  }
  __syncthreads();
#pragma unroll
  for (int i = 0; i < 64; i += 16) {
    const int s = lr + i;
    uint2 ov;
    ov.x = (unsigned)tile[lc + 0][s] | ((unsigned)tile[lc + 1][s] << 16);
    ov.y = (unsigned)tile[lc + 2][s] | ((unsigned)tile[lc + 3][s] << 16);
    *(uint2*)(dst + (size_t)((b * 16 + h) * 64 + s) * 1024 + t0 + lc) = ov;
  }
}

// ---------------- inner causal flash attention ------------------------------
// grid (4, H, B): block p processes q-tiles (7-p) then (p) sequentially.
__global__ __launch_bounds__(512) void attn_inner(
    const u16* __restrict__ qkv, const u16* __restrict__ vt,
    u16* __restrict__ att)
{
  __shared__ u16 Kl[128 * 64];
  __shared__ u16 Vl[64 * 128];
  __shared__ u16 Pl[8 * 16 * 128];
  const int p = blockIdx.x, h = blockIdx.y, b = blockIdx.z;
  const int tid = threadIdx.x, wid = tid >> 6, lane = tid & 63;
  const int col = lane & 15, kgr = lane >> 4;
  const float scale = 0.03125f;
  u16* pw = &Pl[wid * 2048];

  auto run_q = [&](int tb) {
    short8 qf[2];
    {
      const int trow = tb * 128 + wid * 16 + col;
      const u16* qp = qkv + (size_t)(b * 1024 + trow) * 3072 + h * 64 + kgr * 8;
      qf[0] = *(const short8*)qp;
      qf[1] = *(const short8*)(qp + 32);
    }
    f32x4 o[4] = {};
    float mrun[4], lrun[4];
#pragma unroll
    for (int r = 0; r < 4; ++r) { mrun[r] = -1e30f; lrun[r] = 0.f; }

    for (int kt = 0; kt <= tb * 128; kt += 128) {
#pragma unroll
      for (int i = 0; i < 2; ++i) {
        const int e = i * 4096 + tid * 8;
        const int rk = e >> 6, uk = (e >> 3) & 7;
        gload16(qkv + (size_t)(b * 1024 + kt + rk) * 3072 + 1024 + h * 64 +
                    ((uk ^ (rk & 7)) << 3),
                &Kl[i * 4096 + wid * 512]);
        const int rv = e >> 7, uv = (e >> 3) & 15;
        gload16(vt + (size_t)((b * 16 + h) * 64 + rv) * 1024 + kt +
                    ((uv ^ (rv & 7)) << 3),
                &Vl[i * 4096 + wid * 512]);
      }
      __syncthreads();
      f32x4 s[8];
#pragma unroll
      for (int nt = 0; nt < 8; ++nt) {
        const int rk = nt * 16 + col;
        const short8 k0 = *(const short8*)&Kl[rk * 64 + ((kgr ^ (rk & 7)) << 3)];
        const short8 k1 = *(const short8*)&Kl[rk * 64 + (((kgr + 4) ^ (rk & 7)) << 3)];
        f32x4 a = {};
        a = MFMA16(qf[0], k0, a);
        a = MFMA16(qf[1], k1, a);
        s[nt] = a;
      }
      float mx[4];
#pragma unroll
      for (int r = 0; r < 4; ++r) mx[r] = -1e30f;
      const int tbase = tb * 128 + wid * 16 + kgr * 4;
      if (kt == tb * 128) {
#pragma unroll
        for (int nt = 0; nt < 8; ++nt) {
          const int kp = kt + nt * 16 + col;
#pragma unroll
          for (int r = 0; r < 4; ++r) {
            float v = s[nt][r] * scale;
            if (kp > tbase + r) v = -1e30f;
            s[nt][r] = v;
            mx[r] = fmaxf(mx[r], v);
          }
        }
      } else {
#pragma unroll
        for (int nt = 0; nt < 8; ++nt)
#pragma unroll
          for (int r = 0; r < 4; ++r) {
            const float v = s[nt][r] * scale;
            s[nt][r] = v;
            mx[r] = fmaxf(mx[r], v);
          }
      }
#pragma unroll
      for (int r = 0; r < 4; ++r)
#pragma unroll
        for (int off = 1; off < 16; off <<= 1)
          mx[r] = fmaxf(mx[r], __shfl_xor(mx[r], off));
      float f[4], rs[4];
#pragma unroll
      for (int r = 0; r < 4; ++r) {
        const float mn = fmaxf(mrun[r], mx[r]);
        f[r] = __expf(mrun[r] - mn);
        mrun[r] = mn;
        rs[r] = 0.f;
      }
#pragma unroll
      for (int nt = 0; nt < 8; ++nt)
#pragma unroll
        for (int r = 0; r < 4; ++r) {
          const float pv = __expf(s[nt][r] - mrun[r]);
          s[nt][r] = pv;
          rs[r] += pv;
        }
#pragma unroll
      for (int r = 0; r < 4; ++r) {
#pragma unroll
        for (int off = 1; off < 16; off <<= 1)
          rs[r] += __shfl_xor(rs[r], off);
        lrun[r] = lrun[r] * f[r] + rs[r];
      }
#pragma unroll
      for (int st = 0; st < 4; ++st)
#pragma unroll
        for (int r = 0; r < 4; ++r)
          o[st][r] *= f[r];
#pragma unroll
      for (int nt = 0; nt < 8; ++nt)
#pragma unroll
        for (int r = 0; r < 4; ++r) {
          const int rp = kgr * 4 + r;
          pw[rp * 128 + ((nt * 16 + col) ^ ((rp & 7) << 3))] = f2bf(s[nt][r]);
        }
#pragma unroll
      for (int ks = 0; ks < 4; ++ks) {
        const short8 pa = *(const short8*)&pw[col * 128 +
            ((ks * 32 + kgr * 8) ^ ((col & 7) << 3))];
#pragma unroll
        for (int st = 0; st < 4; ++st) {
          const int rv = st * 16 + col;
          const short8 vb = *(const short8*)&Vl[rv * 128 +
              (((ks * 4 + kgr) ^ (rv & 7)) << 3)];
          o[st] = MFMA16(pa, vb, o[st]);
        }
      }
      __syncthreads();
    }
#pragma unroll
    for (int r = 0; r < 4; ++r) {
      const float inv = 1.f / lrun[r];
      const int t = tb * 128 + wid * 16 + kgr * 4 + r;
#pragma unroll
      for (int st = 0; st < 4; ++st)
        att[(size_t)(b * 1024 + t) * 1024 + h * 64 + st * 16 + col] =
            f2bf(o[st][r] * inv);
    }
  };

  run_q(7 - p);
  run_q(p);
}

// ---------------- compressing cross attention -------------------------------
__global__ __launch_bounds__(512) void attn_cross(
    const u16* __restrict__ qv, const u16* __restrict__ kk,
    const u16* __restrict__ vt, u16* __restrict__ outc)
{
  __shared__ u16 KKl[256 * 64];
  __shared__ u16 Vl[64 * 128];
  __shared__ u16 PTl[256 * 128];
  const int h = blockIdx.x, b = blockIdx.y;
  const int tid = threadIdx.x, wid = tid >> 6, lane = tid & 63;
  const int col = lane & 15, kgr = lane >> 4;
  const float scale = 0.03125f;
#pragma unroll
  for (int i = 0; i < 4; ++i) {
    const int e = i * 4096 + tid * 8;
    const int rk = e >> 6, uk = (e >> 3) & 7;
    gload16(kk + (size_t)rk * 1024 + h * 64 + ((uk ^ (rk & 7)) << 3),
            &KKl[i * 4096 + wid * 512]);
  }
  f32x4 oacc[2][4] = {};
  for (int tt = 0; tt < 8; ++tt) {
    const int t0 = tt * 128;
#pragma unroll
    for (int i = 0; i < 2; ++i) {
      const int e = i * 4096 + tid * 8;
      const int rv = e >> 7, uv = (e >> 3) & 15;
      gload16(vt + (size_t)((b * 16 + h) * 64 + rv) * 1024 + t0 +
                  ((uv ^ (rv & 7)) << 3),
              &Vl[i * 4096 + wid * 512]);
    }
    short8 qf0, qf1;
    {
      const int trow = t0 + wid * 16 + col;
      const u16* qp = qv + (size_t)(b * 1024 + trow) * 2048 + h * 64 + kgr * 8;
      qf0 = *(const short8*)qp;
      qf1 = *(const short8*)(qp + 32);
    }
    __syncthreads();
    f32x4 s[16];
#pragma unroll
    for (int rt = 0; rt < 16; ++rt) {
      const int rk = rt * 16 + col;
      const short8 k0 = *(const short8*)&KKl[rk * 64 + ((kgr ^ (rk & 7)) << 3)];
      const short8 k1 = *(const short8*)&KKl[rk * 64 + (((kgr + 4) ^ (rk & 7)) << 3)];
      f32x4 a = {};
      a = MFMA16(qf0, k0, a);
      a = MFMA16(qf1, k1, a);
      s[rt] = a;
    }
    float mx[4];
#pragma unroll
    for (int r = 0; r < 4; ++r) mx[r] = -1e30f;
    const int tbase = t0 + wid * 16 + kgr * 4;
    if (t0 < 256) {
#pragma unroll
      for (int rt = 0; rt < 16; ++rt) {
        const int rp = rt * 16 + col;
#pragma unroll
        for (int r = 0; r < 4; ++r) {
          float v = s[rt][r] * scale;
          if (rp > tbase + r) v = -1e30f;
          s[rt][r] = v;
          mx[r] = fmaxf(mx[r], v);
        }
      }
    } else {
#pragma unroll
      for (int rt = 0; rt < 16; ++rt)
#pragma unroll
        for (int r = 0; r < 4; ++r) {
          const float v = s[rt][r] * scale;
          s[rt][r] = v;
          mx[r] = fmaxf(mx[r], v);
        }
    }
#pragma unroll
    for (int r = 0; r < 4; ++r)
#pragma unroll
      for (int off = 1; off < 16; off <<= 1)
        mx[r] = fmaxf(mx[r], __shfl_xor(mx[r], off));
    float sm[4];
#pragma unroll
    for (int r = 0; r < 4; ++r) sm[r] = 0.f;
#pragma unroll
    for (int rt = 0; rt < 16; ++rt)
#pragma unroll
      for (int r = 0; r < 4; ++r) {
        const float pv = __expf(s[rt][r] - mx[r]);
        s[rt][r] = pv;
        sm[r] += pv;
      }
#pragma unroll
    for (int r = 0; r < 4; ++r) {
#pragma unroll
      for (int off = 1; off < 16; off <<= 1)
        sm[r] += __shfl_xor(sm[r], off);
      sm[r] = 1.f / sm[r];
    }
#pragma unroll
    for (int rt = 0; rt < 16; ++rt)
#pragma unroll
      for (int r = 0; r < 4; ++r) {
        const int rpt = rt * 16 + col;
        PTl[rpt * 128 + ((wid * 16 + kgr * 4 + r) ^ ((rpt & 7) << 3))] =
            f2bf(s[rt][r] * sm[r]);
      }
    __syncthreads();
#pragma unroll
    for (int rr = 0; rr < 2; ++rr) {
      const int rb = (wid * 2 + rr) * 16;
#pragma unroll
      for (int ks = 0; ks < 4; ++ks) {
        const int rpt = rb + col;
        const short8 pa = *(const short8*)&PTl[rpt * 128 +
            ((ks * 32 + kgr * 8) ^ ((rpt & 7) << 3))];
#pragma unroll
        for (int st = 0; st < 4; ++st) {
          const int rv = st * 16 + col;
          const short8 vb = *(const short8*)&Vl[rv * 128 +
              (((ks * 4 + kgr) ^ (rv & 7)) << 3)];
          oacc[rr][st] = MFMA16(pa, vb, oacc[rr][st]);
        }
      }
    }
    __syncthreads();
  }
#pragma unroll
  for (int rr = 0; rr < 2; ++rr)
#pragma unroll
    for (int st = 0; st < 4; ++st)
#pragma unroll
      for (int r = 0; r < 4; ++r) {
        const int rpos = (wid * 2 + rr) * 16 + kgr * 4 + r;
        outc[(size_t)(b * 256 + rpos) * 1024 + h * 64 + st * 16 + col] =
            f2bf(oacc[rr][st][r]);
      }
}

// ---------------- host orchestration ----------------------------------------
extern "C" void kernel_launch(void* const* d_in, const int* in_sizes, int n_in,
                              void* d_out, int out_size, void* d_ws, size_t ws_size,
                              hipStream_t stream)
{
  const float* x     = (const float*)d_in[0];
  const float* pos   = (const float*)d_in[1];
  const float* bln1g = (const float*)d_in[2];
  const float* bln1b = (const float*)d_in[3];
  const float* bwq   = (const float*)d_in[4];
  const float* bwk   = (const float*)d_in[5];
  const float* bwv   = (const float*)d_in[6];
  const float* bwo   = (const float*)d_in[7];
  const float* bbo   = (const float*)d_in[8];
  const float* bln2g = (const float*)d_in[9];
  const float* bln2b = (const float*)d_in[10];
  const float* bw1   = (const float*)d_in[11];
  const float* bb1   = (const float*)d_in[12];
  const float* bw2   = (const float*)d_in[13];
  const float* bb2   = (const float*)d_in[14];
  const float* ln1g  = (const float*)d_in[15];
  const float* ln1b  = (const float*)d_in[16];
  const float* cwq   = (const float*)d_in[17];
  const float* cwk   = (const float*)d_in[18];
  const float* cwv   = (const float*)d_in[19];
  const float* cwo   = (const float*)d_in[20];
  const float* cbo   = (const float*)d_in[21];
  const float* cln2g = (const float*)d_in[22];
  const float* cln2b = (const float*)d_in[23];
  const float* fw1   = (const float*)d_in[24];
  const float* fb1   = (const float*)d_in[25];
  const float* fw2   = (const float*)d_in[26];
  const float* fb2   = (const float*)d_in[27];

  char* ws = (char*)d_ws;
  size_t off = 0;
  auto alloc = [&](size_t bytes) -> void* {
    void* p = ws + off; off += (bytes + 255) & ~(size_t)255; return p;
  };
  u16* wqkv_t = (u16*)alloc((size_t)3072 * 1024 * 2);
  u16* wo_t   = (u16*)alloc((size_t)1024 * 1024 * 2);
  u16* w1_t   = (u16*)alloc((size_t)4096 * 1024 * 2);
  u16* w2_t   = (u16*)alloc((size_t)1024 * 4096 * 2);
  u16* cwqv_t = (u16*)alloc((size_t)2048 * 1024 * 2);
  u16* cwk_t  = (u16*)alloc((size_t)1024 * 1024 * 2);
  u16* cwo_t  = (u16*)alloc((size_t)1024 * 1024 * 2);
  u16* fw1_t  = (u16*)alloc((size_t)4096 * 1024 * 2);
  u16* fw2_t  = (u16*)alloc((size_t)1024 * 4096 * 2);
  u16* pos_bf = (u16*)alloc((size_t)256 * 1024 * 2);
  u16* kkb    = (u16*)alloc((size_t)256 * 1024 * 2);
  u16* act_ln = (u16*)alloc((size_t)8192 * 1024 * 2);
  u16* qkv    = (u16*)alloc((size_t)8192 * 3072 * 2);
  u16* att    = (u16*)alloc((size_t)8192 * 1024 * 2);
  u16* ffb    = (u16*)alloc((size_t)8192 * 4096 * 2);
  float* yb   = (float*)alloc((size_t)8192 * 1024 * 4);
  if (ws_size < off) return;
  float* x2   = (float*)qkv;
  u16*   qv   = qkv;
  u16*   vt   = ffb;
  u16*   outc = att;
  float* zb   = yb;
  float* outp = (float*)d_out;

  const dim3 B256(256), B512(512);
  pack_head_w<<<dim3(2, 32, 16), B256, 0, stream>>>(bwq, wqkv_t);
  pack_head_w<<<dim3(2, 32, 16), B256, 0, stream>>>(bwk, wqkv_t + 1024 * 1024);
  pack_head_w<<<dim3(2, 32, 16), B256, 0, stream>>>(bwv, wqkv_t + 2048 * 1024);
  transpose_w<<<dim3(32, 32),  B256, 0, stream>>>(bwo, wo_t, 1024, 1024);
  transpose_w<<<dim3(128, 32), B256, 0, stream>>>(bw1, w1_t, 1024, 4096);
  transpose_w<<<dim3(32, 128), B256, 0, stream>>>(bw2, w2_t, 4096, 1024);
  pack_head_w<<<dim3(2, 32, 16), B256, 0, stream>>>(cwq, cwqv_t);
  pack_head_w<<<dim3(2, 32, 16), B256, 0, stream>>>(cwv, cwqv_t + 1024 * 1024);
  pack_head_w<<<dim3(2, 32, 16), B256, 0, stream>>>(cwk, cwk_t);
  transpose_w<<<dim3(32, 32),  B256, 0, stream>>>(cwo, cwo_t, 1024, 1024);
  transpose_w<<<dim3(128, 32), B256, 0, stream>>>(fw1, fw1_t, 1024, 4096);
  transpose_w<<<dim3(32, 128), B256, 0, stream>>>(fw2, fw2_t, 4096, 1024);
  cvt_bf16<<<dim3(256), B256, 0, stream>>>(pos, pos_bf);

  // ---- inner standard block ----
  ln_rows<<<dim3(8192), B256, 0, stream>>>(x, bln1g, bln1b, act_ln);
  gemm256n<<<dim3(32, 24), B256, 0, stream>>>(act_ln, wqkv_t, nullptr, qkv,
      nullptr, nullptr, nullptr, 8192, 3072, 1024, 0);
  vtrans<<<dim3(16, 16, 8), B256, 0, stream>>>(qkv, vt, 2048, 3072);
  attn_inner<<<dim3(4, 16, 8), B512, 0, stream>>>(qkv, vt, att);
  gemm256n<<<dim3(32, 8), B256, 0, stream>>>(att, wo_t, yb, nullptr,
      bbo, x, nullptr, 8192, 1024, 1024, 0);
  ln_rows<<<dim3(8192), B256, 0, stream>>>(yb, bln2g, bln2b, act_ln);
  gemm256n<<<dim3(32, 32), B256, 0, stream>>>(act_ln, w1_t, nullptr, ffb,
      bb1, nullptr, nullptr, 8192, 4096, 1024, 1);
  gemm256n<<<dim3(32, 8), B256, 0, stream>>>(ffb, w2_t, x2, nullptr,
      bb2, yb, x, 8192, 1024, 4096, 0);

  // ---- compressing cross-attention ----
  ln_rows<<<dim3(8192), B256, 0, stream>>>(x2, ln1g, ln1b, act_ln);
  gemm256n<<<dim3(32, 16), B256, 0, stream>>>(act_ln, cwqv_t, nullptr, qv,
      nullptr, nullptr, nullptr, 8192, 2048, 1024, 0);
  gemm256n<<<dim3(1, 8), B256, 0, stream>>>(pos_bf, cwk_t, nullptr, kkb,
      nullptr, nullptr, nullptr, 256, 1024, 1024, 0);
  vtrans<<<dim3(16, 16, 8), B256, 0, stream>>>(qv, vt, 1024, 2048);
  attn_cross<<<dim3(16, 8), B512, 0, stream>>>(qv, kkb, vt, outc);
  gemm256n<<<dim3(8, 8), B256, 0, stream>>>(outc, cwo_t, zb, nullptr,
      cbo, nullptr, nullptr, 2048, 1024, 1024, 0);

  // ---- final FFN ----
  ln_rows<<<dim3(2048), B256, 0, stream>>>(zb, cln2g, cln2b, act_ln);
  gemm256n<<<dim3(8, 32), B256, 0, stream>>>(act_ln, fw1_t, nullptr, ffb,
      fb1, nullptr, nullptr, 2048, 4096, 1024, 1);
  gemm256n<<<dim3(8, 8), B256, 0, stream>>>(ffb, fw2_t, outp, nullptr,
      fb2, zb, nullptr, 2048, 1024, 4096, 0);
}

// Round 12
// 699.499 us; speedup vs baseline: 1.4692x; 1.1446x over previous
//
#include <hip/hip_runtime.h>
#include <stdint.h>

typedef unsigned short u16;
typedef __attribute__((ext_vector_type(8))) short short8;
typedef __attribute__((ext_vector_type(4))) float f32x4;

#define MFMA16(A,B,C) __builtin_amdgcn_mfma_f32_16x16x32_bf16(A,B,C,0,0,0)

static __device__ __forceinline__ u16 f2bf(float f) {
  union { float f; unsigned u; } v; v.f = f;
  unsigned r = v.u + 0x7FFFu + ((v.u >> 16) & 1u);
  return (u16)(r >> 16);
}

static __device__ __forceinline__ void gload16(const void* g, void* l) {
  __builtin_amdgcn_global_load_lds(
      (const __attribute__((address_space(1))) void*)(uintptr_t)g,
      (__attribute__((address_space(3))) void*)(uint32_t)(uintptr_t)l,
      16, 0, 0);
}

// bijective XCD swizzle (m204)
static __device__ __forceinline__ int xcd_swz() {
  const int gx = gridDim.x, gy = gridDim.y, nwg = gx * gy;
  const int orig = blockIdx.y * gx + blockIdx.x;
  const int q = nwg >> 3, rm = nwg & 7, xcd = orig & 7, idx = orig >> 3;
  return (xcd < rm ? xcd * (q + 1) : rm * (q + 1) + (xcd - rm) * q) + idx;
}

// ======== 128x128 bf16 GEMM, 2-phase counted-vmcnt, 3-deep kh rotation ======
// r8 skeleton (proven 720us total) with ONE change: the 4 kh-units of 64KB
// double-buffer become a 3-unit rotation (48KB) -> 3 blocks/CU (was 2).
// Unit u = 16KB {A[128][32] | B[128][32]} covering k in [u*32,(u+1)*32).
// Ledger: prologue stage(0),stage(1), vmcnt(4) retires u0 (in-flight u1=4).
// Phase u reads b[u%3]; PRE stages u+2 into b[(u+2)%3], whose reader (phase
// u-1) sealed at its end barrier (each wave's ds_reads drained at its own
// lgkmcnt(0) before that barrier). TAIL: in-flight = stage(u+2)+stage(u+1)=8;
// vmcnt(4) retires u+1 needed next phase; edges vmcnt(0). XOR swizzle
// (row>>1)&3 on 16B slots, pre-swizzled source (0 conflicts r4-r11 PMC).
#define GPH(CUR, STAGE_STMT, TAIL_STMT) do { \
  short8 af_[4], bf_[4]; \
  _Pragma("unroll") \
  for (int mf = 0; mf < 4; ++mf) { \
    const int r = wm0 + mf * 16 + colL; \
    af_[mf] = *(const short8*)&lds[(CUR) + r * 32 + ((kgr ^ ((r >> 1) & 3)) << 3)]; \
  } \
  _Pragma("unroll") \
  for (int nf = 0; nf < 4; ++nf) { \
    const int r = wn0 + nf * 16 + colL; \
    bf_[nf] = *(const short8*)&lds[(CUR) + 4096 + r * 32 + ((kgr ^ ((r >> 1) & 3)) << 3)]; \
  } \
  STAGE_STMT; \
  __builtin_amdgcn_s_barrier(); \
  asm volatile("s_waitcnt lgkmcnt(0)" ::: "memory"); \
  __builtin_amdgcn_sched_barrier(0); \
  __builtin_amdgcn_s_setprio(1); \
  _Pragma("unroll") \
  for (int mf = 0; mf < 4; ++mf) \
    _Pragma("unroll") \
    for (int nf = 0; nf < 4; ++nf) \
      acc[mf][nf] = MFMA16(af_[mf], bf_[nf], acc[mf][nf]); \
  __builtin_amdgcn_s_setprio(0); \
  __builtin_amdgcn_sched_barrier(0); \
  TAIL_STMT; \
  __builtin_amdgcn_s_barrier(); \
} while (0)

__global__ __launch_bounds__(256) void gemm128p(
    const u16* __restrict__ A, const u16* __restrict__ Wt,
    float* __restrict__ Cf, u16* __restrict__ Cb,
    const float* __restrict__ bias,
    const float* __restrict__ res1, const float* __restrict__ res2,
    int M, int N, int K, int relu)
{
  __shared__ u16 lds[24576];  // 48 KiB = 3 units x 8192 elems
  const int tid = threadIdx.x;
  const int wid = tid >> 6, lane = tid & 63;
  const int colL = lane & 15, kgr = lane >> 4;
  const int wm0 = (wid & 1) * 64, wn0 = (wid >> 1) * 64;
  const int w = xcd_swz();
  const int m0 = (w / gridDim.y) * 128, n0 = (w % gridDim.y) * 128;
  const int U = K >> 5;  // number of 32-wide kh-units
  f32x4 acc[4][4] = {};

  // stage unit u into buffer at elem offset bufo: 4 gload16/thread.
  auto stageP = [&](int u, int bufo) {
    const int kb = u * 32;
#pragma unroll
    for (int i = 0; i < 2; ++i) {
      const int c = i * 256 + tid;
      const int row = c >> 2, slot = c & 3;
      const int cs = kb + ((slot ^ ((row >> 1) & 3)) << 3);
      gload16(A  + (size_t)(m0 + row) * K + cs,
              &lds[bufo + ((i * 256 + wid * 64) << 3)]);
      gload16(Wt + (size_t)(n0 + row) * K + cs,
              &lds[bufo + 4096 + ((i * 256 + wid * 64) << 3)]);
    }
  };

  int c0 = 0, c1 = 8192, c2 = 16384;
  stageP(0, c0); stageP(1, c1);
  asm volatile("s_waitcnt vmcnt(4)" ::: "memory");  // unit 0 done
  __builtin_amdgcn_s_barrier();

  for (int u = 0; u < U; ++u) {
    GPH(c0,
        { if (u + 2 < U) stageP(u + 2, c2); },
        { if (u + 2 < U) { asm volatile("s_waitcnt vmcnt(4)" ::: "memory"); }
          else           { asm volatile("s_waitcnt vmcnt(0)" ::: "memory"); } });
    const int tmp = c0; c0 = c1; c1 = c2; c2 = tmp;
  }

#pragma unroll
  for (int mf = 0; mf < 4; ++mf) {
#pragma unroll
    for (int nf = 0; nf < 4; ++nf) {
      const int n = n0 + wn0 + nf * 16 + colL;
      const float bv = bias ? bias[n] : 0.f;
#pragma unroll
      for (int rr = 0; rr < 4; ++rr) {
        const int m = m0 + wm0 + mf * 16 + kgr * 4 + rr;
        const size_t off = (size_t)m * N + n;
        float v = acc[mf][nf][rr] + bv;
        if (res1) v += res1[off];
        if (res2) v += res2[off];
        if (relu) v = fmaxf(v, 0.f);
        if (Cf) Cf[off] = v; else Cb[off] = f2bf(v);
      }
    }
  }
}

// ---------------- LayerNorm (fp32 in, bf16 out) -----------------------------
__global__ __launch_bounds__(256) void ln_rows(
    const float* __restrict__ x, const float* __restrict__ g,
    const float* __restrict__ bt, u16* __restrict__ out)
{
  const int row = blockIdx.x, tid = threadIdx.x;
  const float4 v = ((const float4*)(x + (size_t)row * 1024))[tid];
  float s  = v.x + v.y + v.z + v.w;
  float ss = v.x * v.x + v.y * v.y + v.z * v.z + v.w * v.w;
#pragma unroll
  for (int off = 32; off; off >>= 1) {
    s  += __shfl_xor(s, off);
    ss += __shfl_xor(ss, off);
  }
  __shared__ float red[8];
  const int wid = tid >> 6, lane = tid & 63;
  if (lane == 0) { red[wid] = s; red[4 + wid] = ss; }
  __syncthreads();
  s  = red[0] + red[1] + red[2] + red[3];
  ss = red[4] + red[5] + red[6] + red[7];
  const float mean = s * 0.0009765625f;
  const float var  = ss * 0.0009765625f - mean * mean;
  const float rstd = rsqrtf(var + 1e-5f);
  const float4 gg = ((const float4*)g)[tid];
  const float4 bb = ((const float4*)bt)[tid];
  uint2 ov;
  ov.x = (unsigned)f2bf((v.x - mean) * rstd * gg.x + bb.x) |
         ((unsigned)f2bf((v.y - mean) * rstd * gg.y + bb.y) << 16);
  ov.y = (unsigned)f2bf((v.z - mean) * rstd * gg.z + bb.z) |
         ((unsigned)f2bf((v.w - mean) * rstd * gg.w + bb.w) << 16);
  *(uint2*)(out + (size_t)row * 1024 + tid * 4) = ov;
}

// ---------------- weight packing --------------------------------------------
__global__ __launch_bounds__(256) void transpose_w(
    const float* __restrict__ in, u16* __restrict__ out, int R, int C)
{
  __shared__ float t[32][33];
  const int c0 = blockIdx.x * 32, r0 = blockIdx.y * 32;
  const int tx = threadIdx.x & 31, ty = threadIdx.x >> 5;
#pragma unroll
  for (int i = 0; i < 32; i += 8)
    t[ty + i][tx] = in[(size_t)(r0 + ty + i) * C + c0 + tx];
  __syncthreads();
#pragma unroll
  for (int i = 0; i < 32; i += 8)
    out[(size_t)(c0 + ty + i) * R + r0 + tx] = f2bf(t[tx][ty + i]);
}

__global__ __launch_bounds__(256) void pack_head_w(
    const float* __restrict__ w, u16* __restrict__ out)
{
  __shared__ float t[32][33];
  const int h = blockIdx.z;
  const int s0 = blockIdx.x * 32, c0 = blockIdx.y * 32;
  const int tx = threadIdx.x & 31, ty = threadIdx.x >> 5;
#pragma unroll
  for (int i = 0; i < 32; i += 8)
    t[ty + i][tx] = w[((size_t)h * 1024 + c0 + ty + i) * 64 + s0 + tx];
  __syncthreads();
#pragma unroll
  for (int i = 0; i < 32; i += 8)
    out[((size_t)h * 64 + s0 + ty + i) * 1024 + c0 + tx] = f2bf(t[tx][ty + i]);
}

__global__ __launch_bounds__(256) void cvt_bf16(
    const float* __restrict__ in, u16* __restrict__ out)
{
  const int i = blockIdx.x * blockDim.x + threadIdx.x;
  const float4 v = ((const float4*)in)[i];
  uint2 ov;
  ov.x = (unsigned)f2bf(v.x) | ((unsigned)f2bf(v.y) << 16);
  ov.y = (unsigned)f2bf(v.z) | ((unsigned)f2bf(v.w) << 16);
  *(uint2*)(out + (size_t)i * 4) = ov;
}

__global__ __launch_bounds__(256) void vtrans(
    const u16* __restrict__ src, u16* __restrict__ dst, int coloff, int ld)
{
  __shared__ u16 tile[64][65];
  const int t0 = blockIdx.x * 64, h = blockIdx.y, b = blockIdx.z;
  const int lr = threadIdx.x >> 4;
  const int lc = (threadIdx.x & 15) * 4;
#pragma unroll
  for (int i = 0; i < 64; i += 16) {
    const u16* sp = src + (size_t)(b * 1024 + t0 + lr + i) * ld + coloff + h * 64 + lc;
    const uint2 v = *(const uint2*)sp;
    tile[lr + i][lc + 0] = (u16)(v.x & 0xffff);
    tile[lr + i][lc + 1] = (u16)(v.x >> 16);
    tile[lr + i][lc + 2] = (u16)(v.y & 0xffff);
    tile[lr + i][lc + 3] = (u16)(v.y >> 16);
  }
  __syncthreads();
#pragma unroll
  for (int i = 0; i < 64; i += 16) {
    const int s = lr + i;
    uint2 ov;
    ov.x = (unsigned)tile[lc + 0][s] | ((unsigned)tile[lc + 1][s] << 16);
    ov.y = (unsigned)tile[lc + 2][s] | ((unsigned)tile[lc + 3][s] << 16);
    *(uint2*)(dst + (size_t)((b * 16 + h) * 64 + s) * 1024 + t0 + lc) = ov;
  }
}

// ---------------- inner causal flash attention ------------------------------
// grid (4, H, B): block p processes q-tiles (7-p) then (p) sequentially.
__global__ __launch_bounds__(512) void attn_inner(
    const u16* __restrict__ qkv, const u16* __restrict__ vt,
    u16* __restrict__ att)
{
  __shared__ u16 Kl[128 * 64];
  __shared__ u16 Vl[64 * 128];
  __shared__ u16 Pl[8 * 16 * 128];
  const int p = blockIdx.x, h = blockIdx.y, b = blockIdx.z;
  const int tid = threadIdx.x, wid = tid >> 6, lane = tid & 63;
  const int col = lane & 15, kgr = lane >> 4;
  const float scale = 0.03125f;
  u16* pw = &Pl[wid * 2048];

  auto run_q = [&](int tb) {
    short8 qf[2];
    {
      const int trow = tb * 128 + wid * 16 + col;
      const u16* qp = qkv + (size_t)(b * 1024 + trow) * 3072 + h * 64 + kgr * 8;
      qf[0] = *(const short8*)qp;
      qf[1] = *(const short8*)(qp + 32);
    }
    f32x4 o[4] = {};
    float mrun[4], lrun[4];
#pragma unroll
    for (int r = 0; r < 4; ++r) { mrun[r] = -1e30f; lrun[r] = 0.f; }

    for (int kt = 0; kt <= tb * 128; kt += 128) {
#pragma unroll
      for (int i = 0; i < 2; ++i) {
        const int e = i * 4096 + tid * 8;
        const int rk = e >> 6, uk = (e >> 3) & 7;
        gload16(qkv + (size_t)(b * 1024 + kt + rk) * 3072 + 1024 + h * 64 +
                    ((uk ^ (rk & 7)) << 3),
                &Kl[i * 4096 + wid * 512]);
        const int rv = e >> 7, uv = (e >> 3) & 15;
        gload16(vt + (size_t)((b * 16 + h) * 64 + rv) * 1024 + kt +
                    ((uv ^ (rv & 7)) << 3),
                &Vl[i * 4096 + wid * 512]);
      }
      __syncthreads();
      f32x4 s[8];
#pragma unroll
      for (int nt = 0; nt < 8; ++nt) {
        const int rk = nt * 16 + col;
        const short8 k0 = *(const short8*)&Kl[rk * 64 + ((kgr ^ (rk & 7)) << 3)];
        const short8 k1 = *(const short8*)&Kl[rk * 64 + (((kgr + 4) ^ (rk & 7)) << 3)];
        f32x4 a = {};
        a = MFMA16(qf[0], k0, a);
        a = MFMA16(qf[1], k1, a);
        s[nt] = a;
      }
      float mx[4];
#pragma unroll
      for (int r = 0; r < 4; ++r) mx[r] = -1e30f;
      const int tbase = tb * 128 + wid * 16 + kgr * 4;
      if (kt == tb * 128) {
#pragma unroll
        for (int nt = 0; nt < 8; ++nt) {
          const int kp = kt + nt * 16 + col;
#pragma unroll
          for (int r = 0; r < 4; ++r) {
            float v = s[nt][r] * scale;
            if (kp > tbase + r) v = -1e30f;
            s[nt][r] = v;
            mx[r] = fmaxf(mx[r], v);
          }
        }
      } else {
#pragma unroll
        for (int nt = 0; nt < 8; ++nt)
#pragma unroll
          for (int r = 0; r < 4; ++r) {
            const float v = s[nt][r] * scale;
            s[nt][r] = v;
            mx[r] = fmaxf(mx[r], v);
          }
      }
#pragma unroll
      for (int r = 0; r < 4; ++r)
#pragma unroll
        for (int off = 1; off < 16; off <<= 1)
          mx[r] = fmaxf(mx[r], __shfl_xor(mx[r], off));
      float f[4], rs[4];
#pragma unroll
      for (int r = 0; r < 4; ++r) {
        const float mn = fmaxf(mrun[r], mx[r]);
        f[r] = __expf(mrun[r] - mn);
        mrun[r] = mn;
        rs[r] = 0.f;
      }
#pragma unroll
      for (int nt = 0; nt < 8; ++nt)
#pragma unroll
        for (int r = 0; r < 4; ++r) {
          const float pv = __expf(s[nt][r] - mrun[r]);
          s[nt][r] = pv;
          rs[r] += pv;
        }
#pragma unroll
      for (int r = 0; r < 4; ++r) {
#pragma unroll
        for (int off = 1; off < 16; off <<= 1)
          rs[r] += __shfl_xor(rs[r], off);
        lrun[r] = lrun[r] * f[r] + rs[r];
      }
#pragma unroll
      for (int st = 0; st < 4; ++st)
#pragma unroll
        for (int r = 0; r < 4; ++r)
          o[st][r] *= f[r];
#pragma unroll
      for (int nt = 0; nt < 8; ++nt)
#pragma unroll
        for (int r = 0; r < 4; ++r) {
          const int rp = kgr * 4 + r;
          pw[rp * 128 + ((nt * 16 + col) ^ ((rp & 7) << 3))] = f2bf(s[nt][r]);
        }
#pragma unroll
      for (int ks = 0; ks < 4; ++ks) {
        const short8 pa = *(const short8*)&pw[col * 128 +
            ((ks * 32 + kgr * 8) ^ ((col & 7) << 3))];
#pragma unroll
        for (int st = 0; st < 4; ++st) {
          const int rv = st * 16 + col;
          const short8 vb = *(const short8*)&Vl[rv * 128 +
              (((ks * 4 + kgr) ^ (rv & 7)) << 3)];
          o[st] = MFMA16(pa, vb, o[st]);
        }
      }
      __syncthreads();
    }
#pragma unroll
    for (int r = 0; r < 4; ++r) {
      const float inv = 1.f / lrun[r];
      const int t = tb * 128 + wid * 16 + kgr * 4 + r;
#pragma unroll
      for (int st = 0; st < 4; ++st)
        att[(size_t)(b * 1024 + t) * 1024 + h * 64 + st * 16 + col] =
            f2bf(o[st][r] * inv);
    }
  };

  run_q(7 - p);
  run_q(p);
}

// ---------------- compressing cross attention -------------------------------
__global__ __launch_bounds__(512) void attn_cross(
    const u16* __restrict__ qv, const u16* __restrict__ kk,
    const u16* __restrict__ vt, u16* __restrict__ outc)
{
  __shared__ u16 KKl[256 * 64];
  __shared__ u16 Vl[64 * 128];
  __shared__ u16 PTl[256 * 128];
  const int h = blockIdx.x, b = blockIdx.y;
  const int tid = threadIdx.x, wid = tid >> 6, lane = tid & 63;
  const int col = lane & 15, kgr = lane >> 4;
  const float scale = 0.03125f;
#pragma unroll
  for (int i = 0; i < 4; ++i) {
    const int e = i * 4096 + tid * 8;
    const int rk = e >> 6, uk = (e >> 3) & 7;
    gload16(kk + (size_t)rk * 1024 + h * 64 + ((uk ^ (rk & 7)) << 3),
            &KKl[i * 4096 + wid * 512]);
  }
  f32x4 oacc[2][4] = {};
  for (int tt = 0; tt < 8; ++tt) {
    const int t0 = tt * 128;
#pragma unroll
    for (int i = 0; i < 2; ++i) {
      const int e = i * 4096 + tid * 8;
      const int rv = e >> 7, uv = (e >> 3) & 15;
      gload16(vt + (size_t)((b * 16 + h) * 64 + rv) * 1024 + t0 +
                  ((uv ^ (rv & 7)) << 3),
              &Vl[i * 4096 + wid * 512]);
    }
    short8 qf0, qf1;
    {
      const int trow = t0 + wid * 16 + col;
      const u16* qp = qv + (size_t)(b * 1024 + trow) * 2048 + h * 64 + kgr * 8;
      qf0 = *(const short8*)qp;
      qf1 = *(const short8*)(qp + 32);
    }
    __syncthreads();
    f32x4 s[16];
#pragma unroll
    for (int rt = 0; rt < 16; ++rt) {
      const int rk = rt * 16 + col;
      const short8 k0 = *(const short8*)&KKl[rk * 64 + ((kgr ^ (rk & 7)) << 3)];
      const short8 k1 = *(const short8*)&KKl[rk * 64 + (((kgr + 4) ^ (rk & 7)) << 3)];
      f32x4 a = {};
      a = MFMA16(qf0, k0, a);
      a = MFMA16(qf1, k1, a);
      s[rt] = a;
    }
    float mx[4];
#pragma unroll
    for (int r = 0; r < 4; ++r) mx[r] = -1e30f;
    const int tbase = t0 + wid * 16 + kgr * 4;
    if (t0 < 256) {
#pragma unroll
      for (int rt = 0; rt < 16; ++rt) {
        const int rp = rt * 16 + col;
#pragma unroll
        for (int r = 0; r < 4; ++r) {
          float v = s[rt][r] * scale;
          if (rp > tbase + r) v = -1e30f;
          s[rt][r] = v;
          mx[r] = fmaxf(mx[r], v);
        }
      }
    } else {
#pragma unroll
      for (int rt = 0; rt < 16; ++rt)
#pragma unroll
        for (int r = 0; r < 4; ++r) {
          const float v = s[rt][r] * scale;
          s[rt][r] = v;
          mx[r] = fmaxf(mx[r], v);
        }
    }
#pragma unroll
    for (int r = 0; r < 4; ++r)
#pragma unroll
      for (int off = 1; off < 16; off <<= 1)
        mx[r] = fmaxf(mx[r], __shfl_xor(mx[r], off));
    float sm[4];
#pragma unroll
    for (int r = 0; r < 4; ++r) sm[r] = 0.f;
#pragma unroll
    for (int rt = 0; rt < 16; ++rt)
#pragma unroll
      for (int r = 0; r < 4; ++r) {
        const float pv = __expf(s[rt][r] - mx[r]);
        s[rt][r] = pv;
        sm[r] += pv;
      }
#pragma unroll
    for (int r = 0; r < 4; ++r) {
#pragma unroll
      for (int off = 1; off < 16; off <<= 1)
        sm[r] += __shfl_xor(sm[r], off);
      sm[r] = 1.f / sm[r];
    }
#pragma unroll
    for (int rt = 0; rt < 16; ++rt)
#pragma unroll
      for (int r = 0; r < 4; ++r) {
        const int rpt = rt * 16 + col;
        PTl[rpt * 128 + ((wid * 16 + kgr * 4 + r) ^ ((rpt & 7) << 3))] =
            f2bf(s[rt][r] * sm[r]);
      }
    __syncthreads();
#pragma unroll
    for (int rr = 0; rr < 2; ++rr) {
      const int rb = (wid * 2 + rr) * 16;
#pragma unroll
      for (int ks = 0; ks < 4; ++ks) {
        const int rpt = rb + col;
        const short8 pa = *(const short8*)&PTl[rpt * 128 +
            ((ks * 32 + kgr * 8) ^ ((rpt & 7) << 3))];
#pragma unroll
        for (int st = 0; st < 4; ++st) {
          const int rv = st * 16 + col;
          const short8 vb = *(const short8*)&Vl[rv * 128 +
              (((ks * 4 + kgr) ^ (rv & 7)) << 3)];
          oacc[rr][st] = MFMA16(pa, vb, oacc[rr][st]);
        }
      }
    }
    __syncthreads();
  }
#pragma unroll
  for (int rr = 0; rr < 2; ++rr)
#pragma unroll
    for (int st = 0; st < 4; ++st)
#pragma unroll
      for (int r = 0; r < 4; ++r) {
        const int rpos = (wid * 2 + rr) * 16 + kgr * 4 + r;
        outc[(size_t)(b * 256 + rpos) * 1024 + h * 64 + st * 16 + col] =
            f2bf(oacc[rr][st][r]);
      }
}

// ---------------- host orchestration ----------------------------------------
extern "C" void kernel_launch(void* const* d_in, const int* in_sizes, int n_in,
                              void* d_out, int out_size, void* d_ws, size_t ws_size,
                              hipStream_t stream)
{
  const float* x     = (const float*)d_in[0];
  const float* pos   = (const float*)d_in[1];
  const float* bln1g = (const float*)d_in[2];
  const float* bln1b = (const float*)d_in[3];
  const float* bwq   = (const float*)d_in[4];
  const float* bwk   = (const float*)d_in[5];
  const float* bwv   = (const float*)d_in[6];
  const float* bwo   = (const float*)d_in[7];
  const float* bbo   = (const float*)d_in[8];
  const float* bln2g = (const float*)d_in[9];
  const float* bln2b = (const float*)d_in[10];
  const float* bw1   = (const float*)d_in[11];
  const float* bb1   = (const float*)d_in[12];
  const float* bw2   = (const float*)d_in[13];
  const float* bb2   = (const float*)d_in[14];
  const float* ln1g  = (const float*)d_in[15];
  const float* ln1b  = (const float*)d_in[16];
  const float* cwq   = (const float*)d_in[17];
  const float* cwk   = (const float*)d_in[18];
  const float* cwv   = (const float*)d_in[19];
  const float* cwo   = (const float*)d_in[20];
  const float* cbo   = (const float*)d_in[21];
  const float* cln2g = (const float*)d_in[22];
  const float* cln2b = (const float*)d_in[23];
  const float* fw1   = (const float*)d_in[24];
  const float* fb1   = (const float*)d_in[25];
  const float* fw2   = (const float*)d_in[26];
  const float* fb2   = (const float*)d_in[27];

  char* ws = (char*)d_ws;
  size_t off = 0;
  auto alloc = [&](size_t bytes) -> void* {
    void* p = ws + off; off += (bytes + 255) & ~(size_t)255; return p;
  };
  u16* wqkv_t = (u16*)alloc((size_t)3072 * 1024 * 2);
  u16* wo_t   = (u16*)alloc((size_t)1024 * 1024 * 2);
  u16* w1_t   = (u16*)alloc((size_t)4096 * 1024 * 2);
  u16* w2_t   = (u16*)alloc((size_t)1024 * 4096 * 2);
  u16* cwqv_t = (u16*)alloc((size_t)2048 * 1024 * 2);
  u16* cwk_t  = (u16*)alloc((size_t)1024 * 1024 * 2);
  u16* cwo_t  = (u16*)alloc((size_t)1024 * 1024 * 2);
  u16* fw1_t  = (u16*)alloc((size_t)4096 * 1024 * 2);
  u16* fw2_t  = (u16*)alloc((size_t)1024 * 4096 * 2);
  u16* pos_bf = (u16*)alloc((size_t)256 * 1024 * 2);
  u16* kkb    = (u16*)alloc((size_t)256 * 1024 * 2);
  u16* act_ln = (u16*)alloc((size_t)8192 * 1024 * 2);
  u16* qkv    = (u16*)alloc((size_t)8192 * 3072 * 2);
  u16* att    = (u16*)alloc((size_t)8192 * 1024 * 2);
  u16* ffb    = (u16*)alloc((size_t)8192 * 4096 * 2);
  float* yb   = (float*)alloc((size_t)8192 * 1024 * 4);
  if (ws_size < off) return;
  float* x2   = (float*)qkv;
  u16*   qv   = qkv;
  u16*   vt   = ffb;
  u16*   outc = att;
  float* zb   = yb;
  float* outp = (float*)d_out;

  const dim3 B256(256), B512(512);
  pack_head_w<<<dim3(2, 32, 16), B256, 0, stream>>>(bwq, wqkv_t);
  pack_head_w<<<dim3(2, 32, 16), B256, 0, stream>>>(bwk, wqkv_t + 1024 * 1024);
  pack_head_w<<<dim3(2, 32, 16), B256, 0, stream>>>(bwv, wqkv_t + 2048 * 1024);
  transpose_w<<<dim3(32, 32),  B256, 0, stream>>>(bwo, wo_t, 1024, 1024);
  transpose_w<<<dim3(128, 32), B256, 0, stream>>>(bw1, w1_t, 1024, 4096);
  transpose_w<<<dim3(32, 128), B256, 0, stream>>>(bw2, w2_t, 4096, 1024);
  pack_head_w<<<dim3(2, 32, 16), B256, 0, stream>>>(cwq, cwqv_t);
  pack_head_w<<<dim3(2, 32, 16), B256, 0, stream>>>(cwv, cwqv_t + 1024 * 1024);
  pack_head_w<<<dim3(2, 32, 16), B256, 0, stream>>>(cwk, cwk_t);
  transpose_w<<<dim3(32, 32),  B256, 0, stream>>>(cwo, cwo_t, 1024, 1024);
  transpose_w<<<dim3(128, 32), B256, 0, stream>>>(fw1, fw1_t, 1024, 4096);
  transpose_w<<<dim3(32, 128), B256, 0, stream>>>(fw2, fw2_t, 4096, 1024);
  cvt_bf16<<<dim3(256), B256, 0, stream>>>(pos, pos_bf);

  // ---- inner standard block ----
  ln_rows<<<dim3(8192), B256, 0, stream>>>(x, bln1g, bln1b, act_ln);
  gemm128p<<<dim3(64, 24), B256, 0, stream>>>(act_ln, wqkv_t, nullptr, qkv,
      nullptr, nullptr, nullptr, 8192, 3072, 1024, 0);
  vtrans<<<dim3(16, 16, 8), B256, 0, stream>>>(qkv, vt, 2048, 3072);
  attn_inner<<<dim3(4, 16, 8), B512, 0, stream>>>(qkv, vt, att);
  gemm128p<<<dim3(64, 8), B256, 0, stream>>>(att, wo_t, yb, nullptr,
      bbo, x, nullptr, 8192, 1024, 1024, 0);
  ln_rows<<<dim3(8192), B256, 0, stream>>>(yb, bln2g, bln2b, act_ln);
  gemm128p<<<dim3(64, 32), B256, 0, stream>>>(act_ln, w1_t, nullptr, ffb,
      bb1, nullptr, nullptr, 8192, 4096, 1024, 1);
  gemm128p<<<dim3(64, 8), B256, 0, stream>>>(ffb, w2_t, x2, nullptr,
      bb2, yb, x, 8192, 1024, 4096, 0);

  // ---- compressing cross-attention ----
  ln_rows<<<dim3(8192), B256, 0, stream>>>(x2, ln1g, ln1b, act_ln);
  gemm128p<<<dim3(64, 16), B256, 0, stream>>>(act_ln, cwqv_t, nullptr, qv,
      nullptr, nullptr, nullptr, 8192, 2048, 1024, 0);
  gemm128p<<<dim3(2, 8), B256, 0, stream>>>(pos_bf, cwk_t, nullptr, kkb,
      nullptr, nullptr, nullptr, 256, 1024, 1024, 0);
  vtrans<<<dim3(16, 16, 8), B256, 0, stream>>>(qv, vt, 1024, 2048);
  attn_cross<<<dim3(16, 8), B512, 0, stream>>>(qv, kkb, vt, outc);
  gemm128p<<<dim3(16, 8), B256, 0, stream>>>(outc, cwo_t, zb, nullptr,
      cbo, nullptr, nullptr, 2048, 1024, 1024, 0);

  // ---- final FFN ----
  ln_rows<<<dim3(2048), B256, 0, stream>>>(zb, cln2g, cln2b, act_ln);
  gemm128p<<<dim3(16, 32), B256, 0, stream>>>(act_ln, fw1_t, nullptr, ffb,
      fb1, nullptr, nullptr, 2048, 4096, 1024, 1);
  gemm128p<<<dim3(16, 8), B256, 0, stream>>>(ffb, fw2_t, outp, nullptr,
      fb2, zb, nullptr, 2048, 1024, 4096, 0);
}

// Round 13
// 696.315 us; speedup vs baseline: 1.4759x; 1.0046x over previous
//
#include <hip/hip_runtime.h>
#include <stdint.h>

typedef unsigned short u16;
typedef __attribute__((ext_vector_type(8))) short short8;
typedef __attribute__((ext_vector_type(4))) float f32x4;

#define MFMA16(A,B,C) __builtin_amdgcn_mfma_f32_16x16x32_bf16(A,B,C,0,0,0)

static __device__ __forceinline__ u16 f2bf(float f) {
  union { float f; unsigned u; } v; v.f = f;
  unsigned r = v.u + 0x7FFFu + ((v.u >> 16) & 1u);
  return (u16)(r >> 16);
}

static __device__ __forceinline__ void gload16(const void* g, void* l) {
  __builtin_amdgcn_global_load_lds(
      (const __attribute__((address_space(1))) void*)(uintptr_t)g,
      (__attribute__((address_space(3))) void*)(uint32_t)(uintptr_t)l,
      16, 0, 0);
}

// bijective XCD swizzle (m204)
static __device__ __forceinline__ int xcd_swz() {
  const int gx = gridDim.x, gy = gridDim.y, nwg = gx * gy;
  const int orig = blockIdx.y * gx + blockIdx.x;
  const int q = nwg >> 3, rm = nwg & 7, xcd = orig & 7, idx = orig >> 3;
  return (xcd < rm ? xcd * (q + 1) : rm * (q + 1) + (xcd - rm) * q) + idx;
}

// ======== 128x128 bf16 GEMM, counted-vmcnt, 3-deep rotation, 1 barrier ======
// r12 (699us, best) with ONE isolated change: BARRIER1 removed (r7 tested this
// confounded with dropping the lgkm-pin/setprio; here those stay).
// Ledger for single-barrier: (RAW) unit u retired by each wave's TAIL vmcnt(4)
// at phase u-1, published by that phase's END barrier, which precedes phase
// u's ds_reads. (WAR) phase u's stage writes b[(u+2)%3]=b[(u-1)%3], issued
// after END barrier of u-1; every reader of that buffer reached the barrier
// only after its lgkmcnt(0) drained its reads. Post-barrier "" memory fence
// stops the compiler hoisting next-phase ds_reads above the barrier.
// 48 KB LDS = 3 units x 16 KB {A[128][32] | B[128][32]} -> 3 blocks/CU.
// XOR swizzle (row>>1)&3 on 16B slots, pre-swizzled source (0 conflicts
// r4-r12 PMC).
#define GPH(CUR, STAGE_STMT, TAIL_STMT) do { \
  short8 af_[4], bf_[4]; \
  _Pragma("unroll") \
  for (int mf = 0; mf < 4; ++mf) { \
    const int r = wm0 + mf * 16 + colL; \
    af_[mf] = *(const short8*)&lds[(CUR) + r * 32 + ((kgr ^ ((r >> 1) & 3)) << 3)]; \
  } \
  _Pragma("unroll") \
  for (int nf = 0; nf < 4; ++nf) { \
    const int r = wn0 + nf * 16 + colL; \
    bf_[nf] = *(const short8*)&lds[(CUR) + 4096 + r * 32 + ((kgr ^ ((r >> 1) & 3)) << 3)]; \
  } \
  STAGE_STMT; \
  asm volatile("s_waitcnt lgkmcnt(0)" ::: "memory"); \
  __builtin_amdgcn_sched_barrier(0); \
  __builtin_amdgcn_s_setprio(1); \
  _Pragma("unroll") \
  for (int mf = 0; mf < 4; ++mf) \
    _Pragma("unroll") \
    for (int nf = 0; nf < 4; ++nf) \
      acc[mf][nf] = MFMA16(af_[mf], bf_[nf], acc[mf][nf]); \
  __builtin_amdgcn_s_setprio(0); \
  __builtin_amdgcn_sched_barrier(0); \
  TAIL_STMT; \
  __builtin_amdgcn_s_barrier(); \
  asm volatile("" ::: "memory"); \
} while (0)

__global__ __launch_bounds__(256) void gemm128p(
    const u16* __restrict__ A, const u16* __restrict__ Wt,
    float* __restrict__ Cf, u16* __restrict__ Cb,
    const float* __restrict__ bias,
    const float* __restrict__ res1, const float* __restrict__ res2,
    int M, int N, int K, int relu)
{
  __shared__ u16 lds[24576];  // 48 KiB = 3 units x 8192 elems
  const int tid = threadIdx.x;
  const int wid = tid >> 6, lane = tid & 63;
  const int colL = lane & 15, kgr = lane >> 4;
  const int wm0 = (wid & 1) * 64, wn0 = (wid >> 1) * 64;
  const int w = xcd_swz();
  const int m0 = (w / gridDim.y) * 128, n0 = (w % gridDim.y) * 128;
  const int U = K >> 5;  // number of 32-wide kh-units
  f32x4 acc[4][4] = {};

  // stage unit u into buffer at elem offset bufo: 4 gload16/thread.
  auto stageP = [&](int u, int bufo) {
    const int kb = u * 32;
#pragma unroll
    for (int i = 0; i < 2; ++i) {
      const int c = i * 256 + tid;
      const int row = c >> 2, slot = c & 3;
      const int cs = kb + ((slot ^ ((row >> 1) & 3)) << 3);
      gload16(A  + (size_t)(m0 + row) * K + cs,
              &lds[bufo + ((i * 256 + wid * 64) << 3)]);
      gload16(Wt + (size_t)(n0 + row) * K + cs,
              &lds[bufo + 4096 + ((i * 256 + wid * 64) << 3)]);
    }
  };

  int c0 = 0, c1 = 8192, c2 = 16384;
  stageP(0, c0); stageP(1, c1);
  asm volatile("s_waitcnt vmcnt(4)" ::: "memory");  // unit 0 done
  __builtin_amdgcn_s_barrier();
  asm volatile("" ::: "memory");

  for (int u = 0; u < U; ++u) {
    GPH(c0,
        { if (u + 2 < U) stageP(u + 2, c2); },
        { if (u + 2 < U) { asm volatile("s_waitcnt vmcnt(4)" ::: "memory"); }
          else           { asm volatile("s_waitcnt vmcnt(0)" ::: "memory"); } });
    const int tmp = c0; c0 = c1; c1 = c2; c2 = tmp;
  }

#pragma unroll
  for (int mf = 0; mf < 4; ++mf) {
#pragma unroll
    for (int nf = 0; nf < 4; ++nf) {
      const int n = n0 + wn0 + nf * 16 + colL;
      const float bv = bias ? bias[n] : 0.f;
#pragma unroll
      for (int rr = 0; rr < 4; ++rr) {
        const int m = m0 + wm0 + mf * 16 + kgr * 4 + rr;
        const size_t off = (size_t)m * N + n;
        float v = acc[mf][nf][rr] + bv;
        if (res1) v += res1[off];
        if (res2) v += res2[off];
        if (relu) v = fmaxf(v, 0.f);
        if (Cf) Cf[off] = v; else Cb[off] = f2bf(v);
      }
    }
  }
}

// ---------------- LayerNorm (fp32 in, bf16 out) -----------------------------
__global__ __launch_bounds__(256) void ln_rows(
    const float* __restrict__ x, const float* __restrict__ g,
    const float* __restrict__ bt, u16* __restrict__ out)
{
  const int row = blockIdx.x, tid = threadIdx.x;
  const float4 v = ((const float4*)(x + (size_t)row * 1024))[tid];
  float s  = v.x + v.y + v.z + v.w;
  float ss = v.x * v.x + v.y * v.y + v.z * v.z + v.w * v.w;
#pragma unroll
  for (int off = 32; off; off >>= 1) {
    s  += __shfl_xor(s, off);
    ss += __shfl_xor(ss, off);
  }
  __shared__ float red[8];
  const int wid = tid >> 6, lane = tid & 63;
  if (lane == 0) { red[wid] = s; red[4 + wid] = ss; }
  __syncthreads();
  s  = red[0] + red[1] + red[2] + red[3];
  ss = red[4] + red[5] + red[6] + red[7];
  const float mean = s * 0.0009765625f;
  const float var  = ss * 0.0009765625f - mean * mean;
  const float rstd = rsqrtf(var + 1e-5f);
  const float4 gg = ((const float4*)g)[tid];
  const float4 bb = ((const float4*)bt)[tid];
  uint2 ov;
  ov.x = (unsigned)f2bf((v.x - mean) * rstd * gg.x + bb.x) |
         ((unsigned)f2bf((v.y - mean) * rstd * gg.y + bb.y) << 16);
  ov.y = (unsigned)f2bf((v.z - mean) * rstd * gg.z + bb.z) |
         ((unsigned)f2bf((v.w - mean) * rstd * gg.w + bb.w) << 16);
  *(uint2*)(out + (size_t)row * 1024 + tid * 4) = ov;
}

// ---------------- weight packing --------------------------------------------
__global__ __launch_bounds__(256) void transpose_w(
    const float* __restrict__ in, u16* __restrict__ out, int R, int C)
{
  __shared__ float t[32][33];
  const int c0 = blockIdx.x * 32, r0 = blockIdx.y * 32;
  const int tx = threadIdx.x & 31, ty = threadIdx.x >> 5;
#pragma unroll
  for (int i = 0; i < 32; i += 8)
    t[ty + i][tx] = in[(size_t)(r0 + ty + i) * C + c0 + tx];
  __syncthreads();
#pragma unroll
  for (int i = 0; i < 32; i += 8)
    out[(size_t)(c0 + ty + i) * R + r0 + tx] = f2bf(t[tx][ty + i]);
}

__global__ __launch_bounds__(256) void pack_head_w(
    const float* __restrict__ w, u16* __restrict__ out)
{
  __shared__ float t[32][33];
  const int h = blockIdx.z;
  const int s0 = blockIdx.x * 32, c0 = blockIdx.y * 32;
  const int tx = threadIdx.x & 31, ty = threadIdx.x >> 5;
#pragma unroll
  for (int i = 0; i < 32; i += 8)
    t[ty + i][tx] = w[((size_t)h * 1024 + c0 + ty + i) * 64 + s0 + tx];
  __syncthreads();
#pragma unroll
  for (int i = 0; i < 32; i += 8)
    out[((size_t)h * 64 + s0 + ty + i) * 1024 + c0 + tx] = f2bf(t[tx][ty + i]);
}

__global__ __launch_bounds__(256) void cvt_bf16(
    const float* __restrict__ in, u16* __restrict__ out)
{
  const int i = blockIdx.x * blockDim.x + threadIdx.x;
  const float4 v = ((const float4*)in)[i];
  uint2 ov;
  ov.x = (unsigned)f2bf(v.x) | ((unsigned)f2bf(v.y) << 16);
  ov.y = (unsigned)f2bf(v.z) | ((unsigned)f2bf(v.w) << 16);
  *(uint2*)(out + (size_t)i * 4) = ov;
}

__global__ __launch_bounds__(256) void vtrans(
    const u16* __restrict__ src, u16* __restrict__ dst, int coloff, int ld)
{
  __shared__ u16 tile[64][65];
  const int t0 = blockIdx.x * 64, h = blockIdx.y, b = blockIdx.z;
  const int lr = threadIdx.x >> 4;
  const int lc = (threadIdx.x & 15) * 4;
#pragma unroll
  for (int i = 0; i < 64; i += 16) {
    const u16* sp = src + (size_t)(b * 1024 + t0 + lr + i) * ld + coloff + h * 64 + lc;
    const uint2 v = *(const uint2*)sp;
    tile[lr + i][lc + 0] = (u16)(v.x & 0xffff);
    tile[lr + i][lc + 1] = (u16)(v.x >> 16);
    tile[lr + i][lc + 2] = (u16)(v.y & 0xffff);
    tile[lr + i][lc + 3] = (u16)(v.y >> 16);
  }
  __syncthreads();
#pragma unroll
  for (int i = 0; i < 64; i += 16) {
    const int s = lr + i;
    uint2 ov;
    ov.x = (unsigned)tile[lc + 0][s] | ((unsigned)tile[lc + 1][s] << 16);
    ov.y = (unsigned)tile[lc + 2][s] | ((unsigned)tile[lc + 3][s] << 16);
    *(uint2*)(dst + (size_t)((b * 16 + h) * 64 + s) * 1024 + t0 + lc) = ov;
  }
}

// ---------------- inner causal flash attention ------------------------------
// grid (4, H, B): block p processes q-tiles (7-p) then (p) sequentially.
__global__ __launch_bounds__(512) void attn_inner(
    const u16* __restrict__ qkv, const u16* __restrict__ vt,
    u16* __restrict__ att)
{
  __shared__ u16 Kl[128 * 64];
  __shared__ u16 Vl[64 * 128];
  __shared__ u16 Pl[8 * 16 * 128];
  const int p = blockIdx.x, h = blockIdx.y, b = blockIdx.z;
  const int tid = threadIdx.x, wid = tid >> 6, lane = tid & 63;
  const int col = lane & 15, kgr = lane >> 4;
  const float scale = 0.03125f;
  u16* pw = &Pl[wid * 2048];

  auto run_q = [&](int tb) {
    short8 qf[2];
    {
      const int trow = tb * 128 + wid * 16 + col;
      const u16* qp = qkv + (size_t)(b * 1024 + trow) * 3072 + h * 64 + kgr * 8;
      qf[0] = *(const short8*)qp;
      qf[1] = *(const short8*)(qp + 32);
    }
    f32x4 o[4] = {};
    float mrun[4], lrun[4];
#pragma unroll
    for (int r = 0; r < 4; ++r) { mrun[r] = -1e30f; lrun[r] = 0.f; }

    for (int kt = 0; kt <= tb * 128; kt += 128) {
#pragma unroll
      for (int i = 0; i < 2; ++i) {
        const int e = i * 4096 + tid * 8;
        const int rk = e >> 6, uk = (e >> 3) & 7;
        gload16(qkv + (size_t)(b * 1024 + kt + rk) * 3072 + 1024 + h * 64 +
                    ((uk ^ (rk & 7)) << 3),
                &Kl[i * 4096 + wid * 512]);
        const int rv = e >> 7, uv = (e >> 3) & 15;
        gload16(vt + (size_t)((b * 16 + h) * 64 + rv) * 1024 + kt +
                    ((uv ^ (rv & 7)) << 3),
                &Vl[i * 4096 + wid * 512]);
      }
      __syncthreads();
      f32x4 s[8];
#pragma unroll
      for (int nt = 0; nt < 8; ++nt) {
        const int rk = nt * 16 + col;
        const short8 k0 = *(const short8*)&Kl[rk * 64 + ((kgr ^ (rk & 7)) << 3)];
        const short8 k1 = *(const short8*)&Kl[rk * 64 + (((kgr + 4) ^ (rk & 7)) << 3)];
        f32x4 a = {};
        a = MFMA16(qf[0], k0, a);
        a = MFMA16(qf[1], k1, a);
        s[nt] = a;
      }
      float mx[4];
#pragma unroll
      for (int r = 0; r < 4; ++r) mx[r] = -1e30f;
      const int tbase = tb * 128 + wid * 16 + kgr * 4;
      if (kt == tb * 128) {
#pragma unroll
        for (int nt = 0; nt < 8; ++nt) {
          const int kp = kt + nt * 16 + col;
#pragma unroll
          for (int r = 0; r < 4; ++r) {
            float v = s[nt][r] * scale;
            if (kp > tbase + r) v = -1e30f;
            s[nt][r] = v;
            mx[r] = fmaxf(mx[r], v);
          }
        }
      } else {
#pragma unroll
        for (int nt = 0; nt < 8; ++nt)
#pragma unroll
          for (int r = 0; r < 4; ++r) {
            const float v = s[nt][r] * scale;
            s[nt][r] = v;
            mx[r] = fmaxf(mx[r], v);
          }
      }
#pragma unroll
      for (int r = 0; r < 4; ++r)
#pragma unroll
        for (int off = 1; off < 16; off <<= 1)
          mx[r] = fmaxf(mx[r], __shfl_xor(mx[r], off));
      float f[4], rs[4];
#pragma unroll
      for (int r = 0; r < 4; ++r) {
        const float mn = fmaxf(mrun[r], mx[r]);
        f[r] = __expf(mrun[r] - mn);
        mrun[r] = mn;
        rs[r] = 0.f;
      }
#pragma unroll
      for (int nt = 0; nt < 8; ++nt)
#pragma unroll
        for (int r = 0; r < 4; ++r) {
          const float pv = __expf(s[nt][r] - mrun[r]);
          s[nt][r] = pv;
          rs[r] += pv;
        }
#pragma unroll
      for (int r = 0; r < 4; ++r) {
#pragma unroll
        for (int off = 1; off < 16; off <<= 1)
          rs[r] += __shfl_xor(rs[r], off);
        lrun[r] = lrun[r] * f[r] + rs[r];
      }
#pragma unroll
      for (int st = 0; st < 4; ++st)
#pragma unroll
        for (int r = 0; r < 4; ++r)
          o[st][r] *= f[r];
#pragma unroll
      for (int nt = 0; nt < 8; ++nt)
#pragma unroll
        for (int r = 0; r < 4; ++r) {
          const int rp = kgr * 4 + r;
          pw[rp * 128 + ((nt * 16 + col) ^ ((rp & 7) << 3))] = f2bf(s[nt][r]);
        }
#pragma unroll
      for (int ks = 0; ks < 4; ++ks) {
        const short8 pa = *(const short8*)&pw[col * 128 +
            ((ks * 32 + kgr * 8) ^ ((col & 7) << 3))];
#pragma unroll
        for (int st = 0; st < 4; ++st) {
          const int rv = st * 16 + col;
          const short8 vb = *(const short8*)&Vl[rv * 128 +
              (((ks * 4 + kgr) ^ (rv & 7)) << 3)];
          o[st] = MFMA16(pa, vb, o[st]);
        }
      }
      __syncthreads();
    }
#pragma unroll
    for (int r = 0; r < 4; ++r) {
      const float inv = 1.f / lrun[r];
      const int t = tb * 128 + wid * 16 + kgr * 4 + r;
#pragma unroll
      for (int st = 0; st < 4; ++st)
        att[(size_t)(b * 1024 + t) * 1024 + h * 64 + st * 16 + col] =
            f2bf(o[st][r] * inv);
    }
  };

  run_q(7 - p);
  run_q(p);
}

// ---------------- compressing cross attention -------------------------------
__global__ __launch_bounds__(512) void attn_cross(
    const u16* __restrict__ qv, const u16* __restrict__ kk,
    const u16* __restrict__ vt, u16* __restrict__ outc)
{
  __shared__ u16 KKl[256 * 64];
  __shared__ u16 Vl[64 * 128];
  __shared__ u16 PTl[256 * 128];
  const int h = blockIdx.x, b = blockIdx.y;
  const int tid = threadIdx.x, wid = tid >> 6, lane = tid & 63;
  const int col = lane & 15, kgr = lane >> 4;
  const float scale = 0.03125f;
#pragma unroll
  for (int i = 0; i < 4; ++i) {
    const int e = i * 4096 + tid * 8;
    const int rk = e >> 6, uk = (e >> 3) & 7;
    gload16(kk + (size_t)rk * 1024 + h * 64 + ((uk ^ (rk & 7)) << 3),
            &KKl[i * 4096 + wid * 512]);
  }
  f32x4 oacc[2][4] = {};
  for (int tt = 0; tt < 8; ++tt) {
    const int t0 = tt * 128;
#pragma unroll
    for (int i = 0; i < 2; ++i) {
      const int e = i * 4096 + tid * 8;
      const int rv = e >> 7, uv = (e >> 3) & 15;
      gload16(vt + (size_t)((b * 16 + h) * 64 + rv) * 1024 + t0 +
                  ((uv ^ (rv & 7)) << 3),
              &Vl[i * 4096 + wid * 512]);
    }
    short8 qf0, qf1;
    {
      const int trow = t0 + wid * 16 + col;
      const u16* qp = qv + (size_t)(b * 1024 + trow) * 2048 + h * 64 + kgr * 8;
      qf0 = *(const short8*)qp;
      qf1 = *(const short8*)(qp + 32);
    }
    __syncthreads();
    f32x4 s[16];
#pragma unroll
    for (int rt = 0; rt < 16; ++rt) {
      const int rk = rt * 16 + col;
      const short8 k0 = *(const short8*)&KKl[rk * 64 + ((kgr ^ (rk & 7)) << 3)];
      const short8 k1 = *(const short8*)&KKl[rk * 64 + (((kgr + 4) ^ (rk & 7)) << 3)];
      f32x4 a = {};
      a = MFMA16(qf0, k0, a);
      a = MFMA16(qf1, k1, a);
      s[rt] = a;
    }
    float mx[4];
#pragma unroll
    for (int r = 0; r < 4; ++r) mx[r] = -1e30f;
    const int tbase = t0 + wid * 16 + kgr * 4;
    if (t0 < 256) {
#pragma unroll
      for (int rt = 0; rt < 16; ++rt) {
        const int rp = rt * 16 + col;
#pragma unroll
        for (int r = 0; r < 4; ++r) {
          float v = s[rt][r] * scale;
          if (rp > tbase + r) v = -1e30f;
          s[rt][r] = v;
          mx[r] = fmaxf(mx[r], v);
        }
      }
    } else {
#pragma unroll
      for (int rt = 0; rt < 16; ++rt)
#pragma unroll
        for (int r = 0; r < 4; ++r) {
          const float v = s[rt][r] * scale;
          s[rt][r] = v;
          mx[r] = fmaxf(mx[r], v);
        }
    }
#pragma unroll
    for (int r = 0; r < 4; ++r)
#pragma unroll
      for (int off = 1; off < 16; off <<= 1)
        mx[r] = fmaxf(mx[r], __shfl_xor(mx[r], off));
    float sm[4];
#pragma unroll
    for (int r = 0; r < 4; ++r) sm[r] = 0.f;
#pragma unroll
    for (int rt = 0; rt < 16; ++rt)
#pragma unroll
      for (int r = 0; r < 4; ++r) {
        const float pv = __expf(s[rt][r] - mx[r]);
        s[rt][r] = pv;
        sm[r] += pv;
      }
#pragma unroll
    for (int r = 0; r < 4; ++r) {
#pragma unroll
      for (int off = 1; off < 16; off <<= 1)
        sm[r] += __shfl_xor(sm[r], off);
      sm[r] = 1.f / sm[r];
    }
#pragma unroll
    for (int rt = 0; rt < 16; ++rt)
#pragma unroll
      for (int r = 0; r < 4; ++r) {
        const int rpt = rt * 16 + col;
        PTl[rpt * 128 + ((wid * 16 + kgr * 4 + r) ^ ((rpt & 7) << 3))] =
            f2bf(s[rt][r] * sm[r]);
      }
    __syncthreads();
#pragma unroll
    for (int rr = 0; rr < 2; ++rr) {
      const int rb = (wid * 2 + rr) * 16;
#pragma unroll
      for (int ks = 0; ks < 4; ++ks) {
        const int rpt = rb + col;
        const short8 pa = *(const short8*)&PTl[rpt * 128 +
            ((ks * 32 + kgr * 8) ^ ((rpt & 7) << 3))];
#pragma unroll
        for (int st = 0; st < 4; ++st) {
          const int rv = st * 16 + col;
          const short8 vb = *(const short8*)&Vl[rv * 128 +
              (((ks * 4 + kgr) ^ (rv & 7)) << 3)];
          oacc[rr][st] = MFMA16(pa, vb, oacc[rr][st]);
        }
      }
    }
    __syncthreads();
  }
#pragma unroll
  for (int rr = 0; rr < 2; ++rr)
#pragma unroll
    for (int st = 0; st < 4; ++st)
#pragma unroll
      for (int r = 0; r < 4; ++r) {
        const int rpos = (wid * 2 + rr) * 16 + kgr * 4 + r;
        outc[(size_t)(b * 256 + rpos) * 1024 + h * 64 + st * 16 + col] =
            f2bf(oacc[rr][st][r]);
      }
}

// ---------------- host orchestration ----------------------------------------
extern "C" void kernel_launch(void* const* d_in, const int* in_sizes, int n_in,
                              void* d_out, int out_size, void* d_ws, size_t ws_size,
                              hipStream_t stream)
{
  const float* x     = (const float*)d_in[0];
  const float* pos   = (const float*)d_in[1];
  const float* bln1g = (const float*)d_in[2];
  const float* bln1b = (const float*)d_in[3];
  const float* bwq   = (const float*)d_in[4];
  const float* bwk   = (const float*)d_in[5];
  const float* bwv   = (const float*)d_in[6];
  const float* bwo   = (const float*)d_in[7];
  const float* bbo   = (const float*)d_in[8];
  const float* bln2g = (const float*)d_in[9];
  const float* bln2b = (const float*)d_in[10];
  const float* bw1   = (const float*)d_in[11];
  const float* bb1   = (const float*)d_in[12];
  const float* bw2   = (const float*)d_in[13];
  const float* bb2   = (const float*)d_in[14];
  const float* ln1g  = (const float*)d_in[15];
  const float* ln1b  = (const float*)d_in[16];
  const float* cwq   = (const float*)d_in[17];
  const float* cwk   = (const float*)d_in[18];
  const float* cwv   = (const float*)d_in[19];
  const float* cwo   = (const float*)d_in[20];
  const float* cbo   = (const float*)d_in[21];
  const float* cln2g = (const float*)d_in[22];
  const float* cln2b = (const float*)d_in[23];
  const float* fw1   = (const float*)d_in[24];
  const float* fb1   = (const float*)d_in[25];
  const float* fw2   = (const float*)d_in[26];
  const float* fb2   = (const float*)d_in[27];

  char* ws = (char*)d_ws;
  size_t off = 0;
  auto alloc = [&](size_t bytes) -> void* {
    void* p = ws + off; off += (bytes + 255) & ~(size_t)255; return p;
  };
  u16* wqkv_t = (u16*)alloc((size_t)3072 * 1024 * 2);
  u16* wo_t   = (u16*)alloc((size_t)1024 * 1024 * 2);
  u16* w1_t   = (u16*)alloc((size_t)4096 * 1024 * 2);
  u16* w2_t   = (u16*)alloc((size_t)1024 * 4096 * 2);
  u16* cwqv_t = (u16*)alloc((size_t)2048 * 1024 * 2);
  u16* cwk_t  = (u16*)alloc((size_t)1024 * 1024 * 2);
  u16* cwo_t  = (u16*)alloc((size_t)1024 * 1024 * 2);
  u16* fw1_t  = (u16*)alloc((size_t)4096 * 1024 * 2);
  u16* fw2_t  = (u16*)alloc((size_t)1024 * 4096 * 2);
  u16* pos_bf = (u16*)alloc((size_t)256 * 1024 * 2);
  u16* kkb    = (u16*)alloc((size_t)256 * 1024 * 2);
  u16* act_ln = (u16*)alloc((size_t)8192 * 1024 * 2);
  u16* qkv    = (u16*)alloc((size_t)8192 * 3072 * 2);
  u16* att    = (u16*)alloc((size_t)8192 * 1024 * 2);
  u16* ffb    = (u16*)alloc((size_t)8192 * 4096 * 2);
  float* yb   = (float*)alloc((size_t)8192 * 1024 * 4);
  if (ws_size < off) return;
  float* x2   = (float*)qkv;
  u16*   qv   = qkv;
  u16*   vt   = ffb;
  u16*   outc = att;
  float* zb   = yb;
  float* outp = (float*)d_out;

  const dim3 B256(256), B512(512);
  pack_head_w<<<dim3(2, 32, 16), B256, 0, stream>>>(bwq, wqkv_t);
  pack_head_w<<<dim3(2, 32, 16), B256, 0, stream>>>(bwk, wqkv_t + 1024 * 1024);
  pack_head_w<<<dim3(2, 32, 16), B256, 0, stream>>>(bwv, wqkv_t + 2048 * 1024);
  transpose_w<<<dim3(32, 32),  B256, 0, stream>>>(bwo, wo_t, 1024, 1024);
  transpose_w<<<dim3(128, 32), B256, 0, stream>>>(bw1, w1_t, 1024, 4096);
  transpose_w<<<dim3(32, 128), B256, 0, stream>>>(bw2, w2_t, 4096, 1024);
  pack_head_w<<<dim3(2, 32, 16), B256, 0, stream>>>(cwq, cwqv_t);
  pack_head_w<<<dim3(2, 32, 16), B256, 0, stream>>>(cwv, cwqv_t + 1024 * 1024);
  pack_head_w<<<dim3(2, 32, 16), B256, 0, stream>>>(cwk, cwk_t);
  transpose_w<<<dim3(32, 32),  B256, 0, stream>>>(cwo, cwo_t, 1024, 1024);
  transpose_w<<<dim3(128, 32), B256, 0, stream>>>(fw1, fw1_t, 1024, 4096);
  transpose_w<<<dim3(32, 128), B256, 0, stream>>>(fw2, fw2_t, 4096, 1024);
  cvt_bf16<<<dim3(256), B256, 0, stream>>>(pos, pos_bf);

  // ---- inner standard block ----
  ln_rows<<<dim3(8192), B256, 0, stream>>>(x, bln1g, bln1b, act_ln);
  gemm128p<<<dim3(64, 24), B256, 0, stream>>>(act_ln, wqkv_t, nullptr, qkv,
      nullptr, nullptr, nullptr, 8192, 3072, 1024, 0);
  vtrans<<<dim3(16, 16, 8), B256, 0, stream>>>(qkv, vt, 2048, 3072);
  attn_inner<<<dim3(4, 16, 8), B512, 0, stream>>>(qkv, vt, att);
  gemm128p<<<dim3(64, 8), B256, 0, stream>>>(att, wo_t, yb, nullptr,
      bbo, x, nullptr, 8192, 1024, 1024, 0);
  ln_rows<<<dim3(8192), B256, 0, stream>>>(yb, bln2g, bln2b, act_ln);
  gemm128p<<<dim3(64, 32), B256, 0, stream>>>(act_ln, w1_t, nullptr, ffb,
      bb1, nullptr, nullptr, 8192, 4096, 1024, 1);
  gemm128p<<<dim3(64, 8), B256, 0, stream>>>(ffb, w2_t, x2, nullptr,
      bb2, yb, x, 8192, 1024, 4096, 0);

  // ---- compressing cross-attention ----
  ln_rows<<<dim3(8192), B256, 0, stream>>>(x2, ln1g, ln1b, act_ln);
  gemm128p<<<dim3(64, 16), B256, 0, stream>>>(act_ln, cwqv_t, nullptr, qv,
      nullptr, nullptr, nullptr, 8192, 2048, 1024, 0);
  gemm128p<<<dim3(2, 8), B256, 0, stream>>>(pos_bf, cwk_t, nullptr, kkb,
      nullptr, nullptr, nullptr, 256, 1024, 1024, 0);
  vtrans<<<dim3(16, 16, 8), B256, 0, stream>>>(qv, vt, 1024, 2048);
  attn_cross<<<dim3(16, 8), B512, 0, stream>>>(qv, kkb, vt, outc);
  gemm128p<<<dim3(16, 8), B256, 0, stream>>>(outc, cwo_t, zb, nullptr,
      cbo, nullptr, nullptr, 2048, 1024, 1024, 0);

  // ---- final FFN ----
  ln_rows<<<dim3(2048), B256, 0, stream>>>(zb, cln2g, cln2b, act_ln);
  gemm128p<<<dim3(16, 32), B256, 0, stream>>>(act_ln, fw1_t, nullptr, ffb,
      fb1, nullptr, nullptr, 2048, 4096, 1024, 1);
  gemm128p<<<dim3(16, 8), B256, 0, stream>>>(ffb, fw2_t, outp, nullptr,
      fb2, zb, nullptr, 2048, 1024, 4096, 0);
}

// Round 14
// 693.124 us; speedup vs baseline: 1.4827x; 1.0046x over previous
//
#include <hip/hip_runtime.h>
#include <stdint.h>

typedef unsigned short u16;
typedef __attribute__((ext_vector_type(8))) short short8;
typedef __attribute__((ext_vector_type(4))) float f32x4;

#define MFMA16(A,B,C) __builtin_amdgcn_mfma_f32_16x16x32_bf16(A,B,C,0,0,0)

static __device__ __forceinline__ u16 f2bf(float f) {
  union { float f; unsigned u; } v; v.f = f;
  unsigned r = v.u + 0x7FFFu + ((v.u >> 16) & 1u);
  return (u16)(r >> 16);
}

static __device__ __forceinline__ void gload16(const void* g, void* l) {
  __builtin_amdgcn_global_load_lds(
      (const __attribute__((address_space(1))) void*)(uintptr_t)g,
      (__attribute__((address_space(3))) void*)(uint32_t)(uintptr_t)l,
      16, 0, 0);
}

// bijective XCD swizzle (m204)
static __device__ __forceinline__ int xcd_swz() {
  const int gx = gridDim.x, gy = gridDim.y, nwg = gx * gy;
  const int orig = blockIdx.y * gx + blockIdx.x;
  const int q = nwg >> 3, rm = nwg & 7, xcd = orig & 7, idx = orig >> 3;
  return (xcd < rm ? xcd * (q + 1) : rm * (q + 1) + (xcd - rm) * q) + idx;
}

// ======== 128x128 bf16 GEMM, counted-vmcnt, 3-deep rotation, UNPINNED =======
// r13 (696us) with ONE isolated change: interior scheduling pins removed
// (lgkmcnt(0) drain + sched_barrier(0) + setprio). r13's duty-cycle math:
// forced full-drain before 16 MFMAs -> 77/(200+77+bar) ~= 23% = measured
// MfmaUtil (the m141 order-pinning failure). Unpinned, the compiler emits
// fine-grained lgkmcnt(4/3/1/0), overlapping ds_read latency with MFMAs
// (m97 style). Boundary stays sealed: counted TAIL vmcnt (ledger unchanged:
// vmcnt counts only stage ops, program order untouched), sched_barrier(0)
// pins the schedule at the barrier, "memory" fences stop load motion across.
// RAW/WAR ledger identical to r12/r13 (3-unit rotation, depth-2 prefetch).
// 48 KB LDS = 3 x 16 KB {A[128][32] | B[128][32]} -> 3 blocks/CU. XOR swizzle
// (row>>1)&3 on 16B slots, pre-swizzled source (0 conflicts r4-r13 PMC).
#define GPH(CUR, STAGE_STMT, TAIL_STMT) do { \
  short8 af_[4], bf_[4]; \
  _Pragma("unroll") \
  for (int mf = 0; mf < 4; ++mf) { \
    const int r = wm0 + mf * 16 + colL; \
    af_[mf] = *(const short8*)&lds[(CUR) + r * 32 + ((kgr ^ ((r >> 1) & 3)) << 3)]; \
  } \
  _Pragma("unroll") \
  for (int nf = 0; nf < 4; ++nf) { \
    const int r = wn0 + nf * 16 + colL; \
    bf_[nf] = *(const short8*)&lds[(CUR) + 4096 + r * 32 + ((kgr ^ ((r >> 1) & 3)) << 3)]; \
  } \
  STAGE_STMT; \
  _Pragma("unroll") \
  for (int mf = 0; mf < 4; ++mf) \
    _Pragma("unroll") \
    for (int nf = 0; nf < 4; ++nf) \
      acc[mf][nf] = MFMA16(af_[mf], bf_[nf], acc[mf][nf]); \
  TAIL_STMT; \
  __builtin_amdgcn_sched_barrier(0); \
  __builtin_amdgcn_s_barrier(); \
  asm volatile("" ::: "memory"); \
} while (0)

__global__ __launch_bounds__(256) void gemm128p(
    const u16* __restrict__ A, const u16* __restrict__ Wt,
    float* __restrict__ Cf, u16* __restrict__ Cb,
    const float* __restrict__ bias,
    const float* __restrict__ res1, const float* __restrict__ res2,
    int M, int N, int K, int relu)
{
  __shared__ u16 lds[24576];  // 48 KiB = 3 units x 8192 elems
  const int tid = threadIdx.x;
  const int wid = tid >> 6, lane = tid & 63;
  const int colL = lane & 15, kgr = lane >> 4;
  const int wm0 = (wid & 1) * 64, wn0 = (wid >> 1) * 64;
  const int w = xcd_swz();
  const int m0 = (w / gridDim.y) * 128, n0 = (w % gridDim.y) * 128;
  const int U = K >> 5;  // number of 32-wide kh-units
  f32x4 acc[4][4] = {};

  // stage unit u into buffer at elem offset bufo: 4 gload16/thread.
  auto stageP = [&](int u, int bufo) {
    const int kb = u * 32;
#pragma unroll
    for (int i = 0; i < 2; ++i) {
      const int c = i * 256 + tid;
      const int row = c >> 2, slot = c & 3;
      const int cs = kb + ((slot ^ ((row >> 1) & 3)) << 3);
      gload16(A  + (size_t)(m0 + row) * K + cs,
              &lds[bufo + ((i * 256 + wid * 64) << 3)]);
      gload16(Wt + (size_t)(n0 + row) * K + cs,
              &lds[bufo + 4096 + ((i * 256 + wid * 64) << 3)]);
    }
  };

  int c0 = 0, c1 = 8192, c2 = 16384;
  stageP(0, c0); stageP(1, c1);
  asm volatile("s_waitcnt vmcnt(4)" ::: "memory");  // unit 0 done
  __builtin_amdgcn_s_barrier();
  asm volatile("" ::: "memory");

  for (int u = 0; u < U; ++u) {
    GPH(c0,
        { if (u + 2 < U) stageP(u + 2, c2); },
        { if (u + 2 < U) { asm volatile("s_waitcnt vmcnt(4)" ::: "memory"); }
          else           { asm volatile("s_waitcnt vmcnt(0)" ::: "memory"); } });
    const int tmp = c0; c0 = c1; c1 = c2; c2 = tmp;
  }

#pragma unroll
  for (int mf = 0; mf < 4; ++mf) {
#pragma unroll
    for (int nf = 0; nf < 4; ++nf) {
      const int n = n0 + wn0 + nf * 16 + colL;
      const float bv = bias ? bias[n] : 0.f;
#pragma unroll
      for (int rr = 0; rr < 4; ++rr) {
        const int m = m0 + wm0 + mf * 16 + kgr * 4 + rr;
        const size_t off = (size_t)m * N + n;
        float v = acc[mf][nf][rr] + bv;
        if (res1) v += res1[off];
        if (res2) v += res2[off];
        if (relu) v = fmaxf(v, 0.f);
        if (Cf) Cf[off] = v; else Cb[off] = f2bf(v);
      }
    }
  }
}

// ---------------- LayerNorm (fp32 in, bf16 out) -----------------------------
__global__ __launch_bounds__(256) void ln_rows(
    const float* __restrict__ x, const float* __restrict__ g,
    const float* __restrict__ bt, u16* __restrict__ out)
{
  const int row = blockIdx.x, tid = threadIdx.x;
  const float4 v = ((const float4*)(x + (size_t)row * 1024))[tid];
  float s  = v.x + v.y + v.z + v.w;
  float ss = v.x * v.x + v.y * v.y + v.z * v.z + v.w * v.w;
#pragma unroll
  for (int off = 32; off; off >>= 1) {
    s  += __shfl_xor(s, off);
    ss += __shfl_xor(ss, off);
  }
  __shared__ float red[8];
  const int wid = tid >> 6, lane = tid & 63;
  if (lane == 0) { red[wid] = s; red[4 + wid] = ss; }
  __syncthreads();
  s  = red[0] + red[1] + red[2] + red[3];
  ss = red[4] + red[5] + red[6] + red[7];
  const float mean = s * 0.0009765625f;
  const float var  = ss * 0.0009765625f - mean * mean;
  const float rstd = rsqrtf(var + 1e-5f);
  const float4 gg = ((const float4*)g)[tid];
  const float4 bb = ((const float4*)bt)[tid];
  uint2 ov;
  ov.x = (unsigned)f2bf((v.x - mean) * rstd * gg.x + bb.x) |
         ((unsigned)f2bf((v.y - mean) * rstd * gg.y + bb.y) << 16);
  ov.y = (unsigned)f2bf((v.z - mean) * rstd * gg.z + bb.z) |
         ((unsigned)f2bf((v.w - mean) * rstd * gg.w + bb.w) << 16);
  *(uint2*)(out + (size_t)row * 1024 + tid * 4) = ov;
}

// ---------------- weight packing --------------------------------------------
__global__ __launch_bounds__(256) void transpose_w(
    const float* __restrict__ in, u16* __restrict__ out, int R, int C)
{
  __shared__ float t[32][33];
  const int c0 = blockIdx.x * 32, r0 = blockIdx.y * 32;
  const int tx = threadIdx.x & 31, ty = threadIdx.x >> 5;
#pragma unroll
  for (int i = 0; i < 32; i += 8)
    t[ty + i][tx] = in[(size_t)(r0 + ty + i) * C + c0 + tx];
  __syncthreads();
#pragma unroll
  for (int i = 0; i < 32; i += 8)
    out[(size_t)(c0 + ty + i) * R + r0 + tx] = f2bf(t[tx][ty + i]);
}

__global__ __launch_bounds__(256) void pack_head_w(
    const float* __restrict__ w, u16* __restrict__ out)
{
  __shared__ float t[32][33];
  const int h = blockIdx.z;
  const int s0 = blockIdx.x * 32, c0 = blockIdx.y * 32;
  const int tx = threadIdx.x & 31, ty = threadIdx.x >> 5;
#pragma unroll
  for (int i = 0; i < 32; i += 8)
    t[ty + i][tx] = w[((size_t)h * 1024 + c0 + ty + i) * 64 + s0 + tx];
  __syncthreads();
#pragma unroll
  for (int i = 0; i < 32; i += 8)
    out[((size_t)h * 64 + s0 + ty + i) * 1024 + c0 + tx] = f2bf(t[tx][ty + i]);
}

__global__ __launch_bounds__(256) void cvt_bf16(
    const float* __restrict__ in, u16* __restrict__ out)
{
  const int i = blockIdx.x * blockDim.x + threadIdx.x;
  const float4 v = ((const float4*)in)[i];
  uint2 ov;
  ov.x = (unsigned)f2bf(v.x) | ((unsigned)f2bf(v.y) << 16);
  ov.y = (unsigned)f2bf(v.z) | ((unsigned)f2bf(v.w) << 16);
  *(uint2*)(out + (size_t)i * 4) = ov;
}

__global__ __launch_bounds__(256) void vtrans(
    const u16* __restrict__ src, u16* __restrict__ dst, int coloff, int ld)
{
  __shared__ u16 tile[64][65];
  const int t0 = blockIdx.x * 64, h = blockIdx.y, b = blockIdx.z;
  const int lr = threadIdx.x >> 4;
  const int lc = (threadIdx.x & 15) * 4;
#pragma unroll
  for (int i = 0; i < 64; i += 16) {
    const u16* sp = src + (size_t)(b * 1024 + t0 + lr + i) * ld + coloff + h * 64 + lc;
    const uint2 v = *(const uint2*)sp;
    tile[lr + i][lc + 0] = (u16)(v.x & 0xffff);
    tile[lr + i][lc + 1] = (u16)(v.x >> 16);
    tile[lr + i][lc + 2] = (u16)(v.y & 0xffff);
    tile[lr + i][lc + 3] = (u16)(v.y >> 16);
  }
  __syncthreads();
#pragma unroll
  for (int i = 0; i < 64; i += 16) {
    const int s = lr + i;
    uint2 ov;
    ov.x = (unsigned)tile[lc + 0][s] | ((unsigned)tile[lc + 1][s] << 16);
    ov.y = (unsigned)tile[lc + 2][s] | ((unsigned)tile[lc + 3][s] << 16);
    *(uint2*)(dst + (size_t)((b * 16 + h) * 64 + s) * 1024 + t0 + lc) = ov;
  }
}

// ---------------- inner causal flash attention ------------------------------
// grid (4, H, B): block p processes q-tiles (7-p) then (p) sequentially.
__global__ __launch_bounds__(512) void attn_inner(
    const u16* __restrict__ qkv, const u16* __restrict__ vt,
    u16* __restrict__ att)
{
  __shared__ u16 Kl[128 * 64];
  __shared__ u16 Vl[64 * 128];
  __shared__ u16 Pl[8 * 16 * 128];
  const int p = blockIdx.x, h = blockIdx.y, b = blockIdx.z;
  const int tid = threadIdx.x, wid = tid >> 6, lane = tid & 63;
  const int col = lane & 15, kgr = lane >> 4;
  const float scale = 0.03125f;
  u16* pw = &Pl[wid * 2048];

  auto run_q = [&](int tb) {
    short8 qf[2];
    {
      const int trow = tb * 128 + wid * 16 + col;
      const u16* qp = qkv + (size_t)(b * 1024 + trow) * 3072 + h * 64 + kgr * 8;
      qf[0] = *(const short8*)qp;
      qf[1] = *(const short8*)(qp + 32);
    }
    f32x4 o[4] = {};
    float mrun[4], lrun[4];
#pragma unroll
    for (int r = 0; r < 4; ++r) { mrun[r] = -1e30f; lrun[r] = 0.f; }

    for (int kt = 0; kt <= tb * 128; kt += 128) {
#pragma unroll
      for (int i = 0; i < 2; ++i) {
        const int e = i * 4096 + tid * 8;
        const int rk = e >> 6, uk = (e >> 3) & 7;
        gload16(qkv + (size_t)(b * 1024 + kt + rk) * 3072 + 1024 + h * 64 +
                    ((uk ^ (rk & 7)) << 3),
                &Kl[i * 4096 + wid * 512]);
        const int rv = e >> 7, uv = (e >> 3) & 15;
        gload16(vt + (size_t)((b * 16 + h) * 64 + rv) * 1024 + kt +
                    ((uv ^ (rv & 7)) << 3),
                &Vl[i * 4096 + wid * 512]);
      }
      __syncthreads();
      f32x4 s[8];
#pragma unroll
      for (int nt = 0; nt < 8; ++nt) {
        const int rk = nt * 16 + col;
        const short8 k0 = *(const short8*)&Kl[rk * 64 + ((kgr ^ (rk & 7)) << 3)];
        const short8 k1 = *(const short8*)&Kl[rk * 64 + (((kgr + 4) ^ (rk & 7)) << 3)];
        f32x4 a = {};
        a = MFMA16(qf[0], k0, a);
        a = MFMA16(qf[1], k1, a);
        s[nt] = a;
      }
      float mx[4];
#pragma unroll
      for (int r = 0; r < 4; ++r) mx[r] = -1e30f;
      const int tbase = tb * 128 + wid * 16 + kgr * 4;
      if (kt == tb * 128) {
#pragma unroll
        for (int nt = 0; nt < 8; ++nt) {
          const int kp = kt + nt * 16 + col;
#pragma unroll
          for (int r = 0; r < 4; ++r) {
            float v = s[nt][r] * scale;
            if (kp > tbase + r) v = -1e30f;
            s[nt][r] = v;
            mx[r] = fmaxf(mx[r], v);
          }
        }
      } else {
#pragma unroll
        for (int nt = 0; nt < 8; ++nt)
#pragma unroll
          for (int r = 0; r < 4; ++r) {
            const float v = s[nt][r] * scale;
            s[nt][r] = v;
            mx[r] = fmaxf(mx[r], v);
          }
      }
#pragma unroll
      for (int r = 0; r < 4; ++r)
#pragma unroll
        for (int off = 1; off < 16; off <<= 1)
          mx[r] = fmaxf(mx[r], __shfl_xor(mx[r], off));
      float f[4], rs[4];
#pragma unroll
      for (int r = 0; r < 4; ++r) {
        const float mn = fmaxf(mrun[r], mx[r]);
        f[r] = __expf(mrun[r] - mn);
        mrun[r] = mn;
        rs[r] = 0.f;
      }
#pragma unroll
      for (int nt = 0; nt < 8; ++nt)
#pragma unroll
        for (int r = 0; r < 4; ++r) {
          const float pv = __expf(s[nt][r] - mrun[r]);
          s[nt][r] = pv;
          rs[r] += pv;
        }
#pragma unroll
      for (int r = 0; r < 4; ++r) {
#pragma unroll
        for (int off = 1; off < 16; off <<= 1)
          rs[r] += __shfl_xor(rs[r], off);
        lrun[r] = lrun[r] * f[r] + rs[r];
      }
#pragma unroll
      for (int st = 0; st < 4; ++st)
#pragma unroll
        for (int r = 0; r < 4; ++r)
          o[st][r] *= f[r];
#pragma unroll
      for (int nt = 0; nt < 8; ++nt)
#pragma unroll
        for (int r = 0; r < 4; ++r) {
          const int rp = kgr * 4 + r;
          pw[rp * 128 + ((nt * 16 + col) ^ ((rp & 7) << 3))] = f2bf(s[nt][r]);
        }
#pragma unroll
      for (int ks = 0; ks < 4; ++ks) {
        const short8 pa = *(const short8*)&pw[col * 128 +
            ((ks * 32 + kgr * 8) ^ ((col & 7) << 3))];
#pragma unroll
        for (int st = 0; st < 4; ++st) {
          const int rv = st * 16 + col;
          const short8 vb = *(const short8*)&Vl[rv * 128 +
              (((ks * 4 + kgr) ^ (rv & 7)) << 3)];
          o[st] = MFMA16(pa, vb, o[st]);
        }
      }
      __syncthreads();
    }
#pragma unroll
    for (int r = 0; r < 4; ++r) {
      const float inv = 1.f / lrun[r];
      const int t = tb * 128 + wid * 16 + kgr * 4 + r;
#pragma unroll
      for (int st = 0; st < 4; ++st)
        att[(size_t)(b * 1024 + t) * 1024 + h * 64 + st * 16 + col] =
            f2bf(o[st][r] * inv);
    }
  };

  run_q(7 - p);
  run_q(p);
}

// ---------------- compressing cross attention -------------------------------
__global__ __launch_bounds__(512) void attn_cross(
    const u16* __restrict__ qv, const u16* __restrict__ kk,
    const u16* __restrict__ vt, u16* __restrict__ outc)
{
  __shared__ u16 KKl[256 * 64];
  __shared__ u16 Vl[64 * 128];
  __shared__ u16 PTl[256 * 128];
  const int h = blockIdx.x, b = blockIdx.y;
  const int tid = threadIdx.x, wid = tid >> 6, lane = tid & 63;
  const int col = lane & 15, kgr = lane >> 4;
  const float scale = 0.03125f;
#pragma unroll
  for (int i = 0; i < 4; ++i) {
    const int e = i * 4096 + tid * 8;
    const int rk = e >> 6, uk = (e >> 3) & 7;
    gload16(kk + (size_t)rk * 1024 + h * 64 + ((uk ^ (rk & 7)) << 3),
            &KKl[i * 4096 + wid * 512]);
  }
  f32x4 oacc[2][4] = {};
  for (int tt = 0; tt < 8; ++tt) {
    const int t0 = tt * 128;
#pragma unroll
    for (int i = 0; i < 2; ++i) {
      const int e = i * 4096 + tid * 8;
      const int rv = e >> 7, uv = (e >> 3) & 15;
      gload16(vt + (size_t)((b * 16 + h) * 64 + rv) * 1024 + t0 +
                  ((uv ^ (rv & 7)) << 3),
              &Vl[i * 4096 + wid * 512]);
    }
    short8 qf0, qf1;
    {
      const int trow = t0 + wid * 16 + col;
      const u16* qp = qv + (size_t)(b * 1024 + trow) * 2048 + h * 64 + kgr * 8;
      qf0 = *(const short8*)qp;
      qf1 = *(const short8*)(qp + 32);
    }
    __syncthreads();
    f32x4 s[16];
#pragma unroll
    for (int rt = 0; rt < 16; ++rt) {
      const int rk = rt * 16 + col;
      const short8 k0 = *(const short8*)&KKl[rk * 64 + ((kgr ^ (rk & 7)) << 3)];
      const short8 k1 = *(const short8*)&KKl[rk * 64 + (((kgr + 4) ^ (rk & 7)) << 3)];
      f32x4 a = {};
      a = MFMA16(qf0, k0, a);
      a = MFMA16(qf1, k1, a);
      s[rt] = a;
    }
    float mx[4];
#pragma unroll
    for (int r = 0; r < 4; ++r) mx[r] = -1e30f;
    const int tbase = t0 + wid * 16 + kgr * 4;
    if (t0 < 256) {
#pragma unroll
      for (int rt = 0; rt < 16; ++rt) {
        const int rp = rt * 16 + col;
#pragma unroll
        for (int r = 0; r < 4; ++r) {
          float v = s[rt][r] * scale;
          if (rp > tbase + r) v = -1e30f;
          s[rt][r] = v;
          mx[r] = fmaxf(mx[r], v);
        }
      }
    } else {
#pragma unroll
      for (int rt = 0; rt < 16; ++rt)
#pragma unroll
        for (int r = 0; r < 4; ++r) {
          const float v = s[rt][r] * scale;
          s[rt][r] = v;
          mx[r] = fmaxf(mx[r], v);
        }
    }
#pragma unroll
    for (int r = 0; r < 4; ++r)
#pragma unroll
      for (int off = 1; off < 16; off <<= 1)
        mx[r] = fmaxf(mx[r], __shfl_xor(mx[r], off));
    float sm[4];
#pragma unroll
    for (int r = 0; r < 4; ++r) sm[r] = 0.f;
#pragma unroll
    for (int rt = 0; rt < 16; ++rt)
#pragma unroll
      for (int r = 0; r < 4; ++r) {
        const float pv = __expf(s[rt][r] - mx[r]);
        s[rt][r] = pv;
        sm[r] += pv;
      }
#pragma unroll
    for (int r = 0; r < 4; ++r) {
#pragma unroll
      for (int off = 1; off < 16; off <<= 1)
        sm[r] += __shfl_xor(sm[r], off);
      sm[r] = 1.f / sm[r];
    }
#pragma unroll
    for (int rt = 0; rt < 16; ++rt)
#pragma unroll
      for (int r = 0; r < 4; ++r) {
        const int rpt = rt * 16 + col;
        PTl[rpt * 128 + ((wid * 16 + kgr * 4 + r) ^ ((rpt & 7) << 3))] =
            f2bf(s[rt][r] * sm[r]);
      }
    __syncthreads();
#pragma unroll
    for (int rr = 0; rr < 2; ++rr) {
      const int rb = (wid * 2 + rr) * 16;
#pragma unroll
      for (int ks = 0; ks < 4; ++ks) {
        const int rpt = rb + col;
        const short8 pa = *(const short8*)&PTl[rpt * 128 +
            ((ks * 32 + kgr * 8) ^ ((rpt & 7) << 3))];
#pragma unroll
        for (int st = 0; st < 4; ++st) {
          const int rv = st * 16 + col;
          const short8 vb = *(const short8*)&Vl[rv * 128 +
              (((ks * 4 + kgr) ^ (rv & 7)) << 3)];
          oacc[rr][st] = MFMA16(pa, vb, oacc[rr][st]);
        }
      }
    }
    __syncthreads();
  }
#pragma unroll
  for (int rr = 0; rr < 2; ++rr)
#pragma unroll
    for (int st = 0; st < 4; ++st)
#pragma unroll
      for (int r = 0; r < 4; ++r) {
        const int rpos = (wid * 2 + rr) * 16 + kgr * 4 + r;
        outc[(size_t)(b * 256 + rpos) * 1024 + h * 64 + st * 16 + col] =
            f2bf(oacc[rr][st][r]);
      }
}

// ---------------- host orchestration ----------------------------------------
extern "C" void kernel_launch(void* const* d_in, const int* in_sizes, int n_in,
                              void* d_out, int out_size, void* d_ws, size_t ws_size,
                              hipStream_t stream)
{
  const float* x     = (const float*)d_in[0];
  const float* pos   = (const float*)d_in[1];
  const float* bln1g = (const float*)d_in[2];
  const float* bln1b = (const float*)d_in[3];
  const float* bwq   = (const float*)d_in[4];
  const float* bwk   = (const float*)d_in[5];
  const float* bwv   = (const float*)d_in[6];
  const float* bwo   = (const float*)d_in[7];
  const float* bbo   = (const float*)d_in[8];
  const float* bln2g = (const float*)d_in[9];
  const float* bln2b = (const float*)d_in[10];
  const float* bw1   = (const float*)d_in[11];
  const float* bb1   = (const float*)d_in[12];
  const float* bw2   = (const float*)d_in[13];
  const float* bb2   = (const float*)d_in[14];
  const float* ln1g  = (const float*)d_in[15];
  const float* ln1b  = (const float*)d_in[16];
  const float* cwq   = (const float*)d_in[17];
  const float* cwk   = (const float*)d_in[18];
  const float* cwv   = (const float*)d_in[19];
  const float* cwo   = (const float*)d_in[20];
  const float* cbo   = (const float*)d_in[21];
  const float* cln2g = (const float*)d_in[22];
  const float* cln2b = (const float*)d_in[23];
  const float* fw1   = (const float*)d_in[24];
  const float* fb1   = (const float*)d_in[25];
  const float* fw2   = (const float*)d_in[26];
  const float* fb2   = (const float*)d_in[27];

  char* ws = (char*)d_ws;
  size_t off = 0;
  auto alloc = [&](size_t bytes) -> void* {
    void* p = ws + off; off += (bytes + 255) & ~(size_t)255; return p;
  };
  u16* wqkv_t = (u16*)alloc((size_t)3072 * 1024 * 2);
  u16* wo_t   = (u16*)alloc((size_t)1024 * 1024 * 2);
  u16* w1_t   = (u16*)alloc((size_t)4096 * 1024 * 2);
  u16* w2_t   = (u16*)alloc((size_t)1024 * 4096 * 2);
  u16* cwqv_t = (u16*)alloc((size_t)2048 * 1024 * 2);
  u16* cwk_t  = (u16*)alloc((size_t)1024 * 1024 * 2);
  u16* cwo_t  = (u16*)alloc((size_t)1024 * 1024 * 2);
  u16* fw1_t  = (u16*)alloc((size_t)4096 * 1024 * 2);
  u16* fw2_t  = (u16*)alloc((size_t)1024 * 4096 * 2);
  u16* pos_bf = (u16*)alloc((size_t)256 * 1024 * 2);
  u16* kkb    = (u16*)alloc((size_t)256 * 1024 * 2);
  u16* act_ln = (u16*)alloc((size_t)8192 * 1024 * 2);
  u16* qkv    = (u16*)alloc((size_t)8192 * 3072 * 2);
  u16* att    = (u16*)alloc((size_t)8192 * 1024 * 2);
  u16* ffb    = (u16*)alloc((size_t)8192 * 4096 * 2);
  float* yb   = (float*)alloc((size_t)8192 * 1024 * 4);
  if (ws_size < off) return;
  float* x2   = (float*)qkv;
  u16*   qv   = qkv;
  u16*   vt   = ffb;
  u16*   outc = att;
  float* zb   = yb;
  float* outp = (float*)d_out;

  const dim3 B256(256), B512(512);
  pack_head_w<<<dim3(2, 32, 16), B256, 0, stream>>>(bwq, wqkv_t);
  pack_head_w<<<dim3(2, 32, 16), B256, 0, stream>>>(bwk, wqkv_t + 1024 * 1024);
  pack_head_w<<<dim3(2, 32, 16), B256, 0, stream>>>(bwv, wqkv_t + 2048 * 1024);
  transpose_w<<<dim3(32, 32),  B256, 0, stream>>>(bwo, wo_t, 1024, 1024);
  transpose_w<<<dim3(128, 32), B256, 0, stream>>>(bw1, w1_t, 1024, 4096);
  transpose_w<<<dim3(32, 128), B256, 0, stream>>>(bw2, w2_t, 4096, 1024);
  pack_head_w<<<dim3(2, 32, 16), B256, 0, stream>>>(cwq, cwqv_t);
  pack_head_w<<<dim3(2, 32, 16), B256, 0, stream>>>(cwv, cwqv_t + 1024 * 1024);
  pack_head_w<<<dim3(2, 32, 16), B256, 0, stream>>>(cwk, cwk_t);
  transpose_w<<<dim3(32, 32),  B256, 0, stream>>>(cwo, cwo_t, 1024, 1024);
  transpose_w<<<dim3(128, 32), B256, 0, stream>>>(fw1, fw1_t, 1024, 4096);
  transpose_w<<<dim3(32, 128), B256, 0, stream>>>(fw2, fw2_t, 4096, 1024);
  cvt_bf16<<<dim3(256), B256, 0, stream>>>(pos, pos_bf);

  // ---- inner standard block ----
  ln_rows<<<dim3(8192), B256, 0, stream>>>(x, bln1g, bln1b, act_ln);
  gemm128p<<<dim3(64, 24), B256, 0, stream>>>(act_ln, wqkv_t, nullptr, qkv,
      nullptr, nullptr, nullptr, 8192, 3072, 1024, 0);
  vtrans<<<dim3(16, 16, 8), B256, 0, stream>>>(qkv, vt, 2048, 3072);
  attn_inner<<<dim3(4, 16, 8), B512, 0, stream>>>(qkv, vt, att);
  gemm128p<<<dim3(64, 8), B256, 0, stream>>>(att, wo_t, yb, nullptr,
      bbo, x, nullptr, 8192, 1024, 1024, 0);
  ln_rows<<<dim3(8192), B256, 0, stream>>>(yb, bln2g, bln2b, act_ln);
  gemm128p<<<dim3(64, 32), B256, 0, stream>>>(act_ln, w1_t, nullptr, ffb,
      bb1, nullptr, nullptr, 8192, 4096, 1024, 1);
  gemm128p<<<dim3(64, 8), B256, 0, stream>>>(ffb, w2_t, x2, nullptr,
      bb2, yb, x, 8192, 1024, 4096, 0);

  // ---- compressing cross-attention ----
  ln_rows<<<dim3(8192), B256, 0, stream>>>(x2, ln1g, ln1b, act_ln);
  gemm128p<<<dim3(64, 16), B256, 0, stream>>>(act_ln, cwqv_t, nullptr, qv,
      nullptr, nullptr, nullptr, 8192, 2048, 1024, 0);
  gemm128p<<<dim3(2, 8), B256, 0, stream>>>(pos_bf, cwk_t, nullptr, kkb,
      nullptr, nullptr, nullptr, 256, 1024, 1024, 0);
  vtrans<<<dim3(16, 16, 8), B256, 0, stream>>>(qv, vt, 1024, 2048);
  attn_cross<<<dim3(16, 8), B512, 0, stream>>>(qv, kkb, vt, outc);
  gemm128p<<<dim3(16, 8), B256, 0, stream>>>(outc, cwo_t, zb, nullptr,
      cbo, nullptr, nullptr, 2048, 1024, 1024, 0);

  // ---- final FFN ----
  ln_rows<<<dim3(2048), B256, 0, stream>>>(zb, cln2g, cln2b, act_ln);
  gemm128p<<<dim3(16, 32), B256, 0, stream>>>(act_ln, fw1_t, nullptr, ffb,
      fb1, nullptr, nullptr, 2048, 4096, 1024, 1);
  gemm128p<<<dim3(16, 8), B256, 0, stream>>>(ffb, fw2_t, outp, nullptr,
      fb2, zb, nullptr, 2048, 1024, 4096, 0);
}